// Round 2
// baseline (308.069 us; speedup 1.0000x reference)
//
#include <hip/hip_runtime.h>
#include <stdint.h>

// B=2, S=2048, H=1024, NH=16, DK=DV=64, M=4096.
// cast/transpose -> QKV gemm (V stored transposed) -> barrier-free flash attn -> out gemm.
// ws layout (u16 elems): X(4096*1024) WqkvT(3072*1024) WoT(1024*1024) Q,K(4096*1024 ea) Vt(4096*1024)
// padbits (64 x u64) live in the tail of d_out (written first, consumed by k_attn, overwritten by k_out).

typedef unsigned short u16;
typedef __attribute__((ext_vector_type(8))) __bf16 bf16x8;
typedef __attribute__((ext_vector_type(4))) float f32x4;

__device__ __forceinline__ u16 f2bf(float f) {
  union { float f; uint32_t u; } v; v.f = f;
  uint32_t r = v.u + 0x7FFFu + ((v.u >> 16) & 1u);  // RNE
  return (u16)(r >> 16);
}

__device__ __forceinline__ void gl_lds16(const u16* g, u16* l) {
  auto gp = reinterpret_cast<const __attribute__((address_space(1))) uint32_t*>(
      reinterpret_cast<uintptr_t>(g));
  auto lp = reinterpret_cast<__attribute__((address_space(3))) uint32_t*>(
      reinterpret_cast<uintptr_t>(l));
  __builtin_amdgcn_global_load_lds(gp, lp, 16, 0, 0);
}

// ---------------- prologue ----------------

__global__ void k_cast(const float* __restrict__ src, u16* __restrict__ dst) {
  int idx = (blockIdx.x * 256 + threadIdx.x) * 4;
  const float4 v = *reinterpret_cast<const float4*>(src + idx);
  uint2 o;
  o.x = (uint32_t)f2bf(v.x) | ((uint32_t)f2bf(v.y) << 16);
  o.y = (uint32_t)f2bf(v.z) | ((uint32_t)f2bf(v.w) << 16);
  *reinterpret_cast<uint2*>(dst + idx) = o;
}

// 1024x1024 transpose+cast, 4 matrices via grid.z
__global__ void k_transpose4(const float* __restrict__ s0, const float* __restrict__ s1,
                             const float* __restrict__ s2, const float* __restrict__ s3,
                             u16* __restrict__ dqkv, u16* __restrict__ dwo) {
  __shared__ float tile[32][33];
  int z = blockIdx.z;
  const float* src = z == 0 ? s0 : (z == 1 ? s1 : (z == 2 ? s2 : s3));
  u16* dst = z < 3 ? dqkv + (size_t)z * 1024 * 1024 : dwo;
  int c0 = blockIdx.x * 32, r0 = blockIdx.y * 32;
  int tx = threadIdx.x, ty = threadIdx.y;  // (32,8)
#pragma unroll
  for (int i = 0; i < 4; ++i)
    tile[ty + i * 8][tx] = src[(size_t)(r0 + ty + i * 8) * 1024 + c0 + tx];
  __syncthreads();
#pragma unroll
  for (int i = 0; i < 4; ++i)
    dst[(size_t)(c0 + ty + i * 8) * 1024 + r0 + tx] = f2bf(tile[tx][ty + i * 8]);
}

// padbits[b*32+j] : bit s set if ids[b][j*64+s]==0. 16 blocks x 256 (wave per (b,j))
__global__ void k_padbits(const int* __restrict__ ids, unsigned long long* __restrict__ pb) {
  int idx = blockIdx.x * 4 + (threadIdx.x >> 6);
  int ln = threadIdx.x & 63;
  int b = idx >> 5, j = idx & 31;
  unsigned long long m = __ballot(ids[b * 2048 + j * 64 + ln] == 0);
  if (ln == 0) pb[idx] = m;
}

// ---------------- GEMM core (m97 structure) ----------------

__device__ __forceinline__ void gemm_tile_acc(
    const u16* __restrict__ A, const u16* __restrict__ Bt, int K,
    int tm, int tn, u16* As, u16* Bs, f32x4 acc[4][4]) {
  const int t = threadIdx.x, wv = t >> 6, ln = t & 63;
  const int wr = (wv & 1) * 64, wc = (wv >> 1) * 64;
  const int lr = ln & 15, q8 = (ln >> 4) * 8;
  const int srow = ln >> 2, scol = (ln & 3) * 8;

  for (int k0 = 0; k0 < K; k0 += 32) {
#pragma unroll
    for (int i = 0; i < 2; ++i) {
      int c = wv + i * 4;
      gl_lds16(A + (size_t)(tm + c * 16 + srow) * K + k0 + scol, As + c * 512 + ln * 8);
      gl_lds16(Bt + (size_t)(tn + c * 16 + srow) * K + k0 + scol, Bs + c * 512 + ln * 8);
    }
    __syncthreads();
    bf16x8 av[4], bv[4];
#pragma unroll
    for (int m = 0; m < 4; ++m)
      av[m] = *reinterpret_cast<const bf16x8*>(As + (wr + m * 16 + lr) * 32 + q8);
#pragma unroll
    for (int n = 0; n < 4; ++n)
      bv[n] = *reinterpret_cast<const bf16x8*>(Bs + (wc + n * 16 + lr) * 32 + q8);
#pragma unroll
    for (int m = 0; m < 4; ++m)
#pragma unroll
      for (int n = 0; n < 4; ++n)
        acc[m][n] = __builtin_amdgcn_mfma_f32_16x16x32_bf16(av[m], bv[n], acc[m][n], 0, 0, 0);
    __syncthreads();
  }
}

// QKV projection. Q,K -> [bh][s][64]; V -> TRANSPOSED [bh][64 d][2048 s]
__global__ __launch_bounds__(256) void k_qkv(
    const u16* __restrict__ X, const u16* __restrict__ Wt,
    const float* __restrict__ bQ, const float* __restrict__ bK, const float* __restrict__ bV,
    u16* __restrict__ Q, u16* __restrict__ Kd, u16* __restrict__ V) {
  __shared__ __align__(16) u16 As[128 * 32];
  __shared__ __align__(16) u16 Bs[128 * 32];
  f32x4 acc[4][4] = {};
  const int tm = blockIdx.x * 128, tn = blockIdx.y * 128;
  gemm_tile_acc(X, Wt, 1024, tm, tn, As, Bs, acc);

  const int t = threadIdx.x, wv = t >> 6, ln = t & 63;
  const int wr = (wv & 1) * 64, wc = (wv >> 1) * 64;
  const int lr = ln & 15, q4 = (ln >> 4) * 4;
  const int which = tn >> 10;  // 0:Q 1:K 2:V (block-uniform)

  if (which < 2) {
    u16* dst = which == 0 ? Q : Kd;
    const float* bias = which == 0 ? bQ : bK;
#pragma unroll
    for (int n = 0; n < 4; ++n) {
      int gc = tn + wc + n * 16 + lr;
      int f = gc & 1023;
      float bb = bias[f];
      int h = f >> 6, dd = f & 63;
#pragma unroll
      for (int m = 0; m < 4; ++m)
#pragma unroll
        for (int r = 0; r < 4; ++r) {
          int gr = tm + wr + m * 16 + q4 + r;
          int b = gr >> 11, s = gr & 2047;
          dst[((size_t)((b * 16 + h) * 2048 + s)) * 64 + dd] = f2bf(acc[m][n][r] + bb);
        }
    }
  } else {
#pragma unroll
    for (int n = 0; n < 4; ++n) {
      int gc = tn + wc + n * 16 + lr;
      int f = gc & 1023;
      float bb = bV[f];
      int h = f >> 6, dd = f & 63;
#pragma unroll
      for (int m = 0; m < 4; ++m) {
        int gr0 = tm + wr + m * 16 + q4;
        int b = gr0 >> 11, s0 = gr0 & 2047;
        uint2 pk;
        pk.x = (uint32_t)f2bf(acc[m][n][0] + bb) | ((uint32_t)f2bf(acc[m][n][1] + bb) << 16);
        pk.y = (uint32_t)f2bf(acc[m][n][2] + bb) | ((uint32_t)f2bf(acc[m][n][3] + bb) << 16);
        *reinterpret_cast<uint2*>(V + ((size_t)((b * 16 + h) * 64 + dd)) * 2048 + s0) = pk;
      }
    }
  }
}

// Output projection -> fp32 out
__global__ __launch_bounds__(256) void k_out(
    const u16* __restrict__ O, const u16* __restrict__ WoT,
    const float* __restrict__ bO, float* __restrict__ out) {
  __shared__ __align__(16) u16 As[128 * 32];
  __shared__ __align__(16) u16 Bs[128 * 32];
  f32x4 acc[4][4] = {};
  const int tm = blockIdx.x * 128, tn = blockIdx.y * 128;
  gemm_tile_acc(O, WoT, 1024, tm, tn, As, Bs, acc);

  const int t = threadIdx.x, wv = t >> 6, ln = t & 63;
  const int wr = (wv & 1) * 64, wc = (wv >> 1) * 64;
  const int lr = ln & 15, q4 = (ln >> 4) * 4;
#pragma unroll
  for (int n = 0; n < 4; ++n) {
    int gc = tn + wc + n * 16 + lr;
    float bb = bO[gc];
#pragma unroll
    for (int m = 0; m < 4; ++m)
#pragma unroll
      for (int r = 0; r < 4; ++r) {
        int gr = tm + wr + m * 16 + q4 + r;
        out[(size_t)gr * 1024 + gc] = acc[m][n][r] + bb;
      }
  }
}

// ---------------- barrier-free flash attention ----------------
// grid (32 qtiles BQ=64, 32 bh), block 128 (2 fully-independent waves, 32 q each).
// Per wave, per k-tile (64 keys): S^T = K·Q^T (A=K frags, B=Q frags, from global);
// mask+online softmax (lane owns a fixed q column: 2 shuffles per reduction);
// P packed to LDS rows [q][s] via ds_write_b64; O^T += V^T·P^T (A=Vt frags from
// global, B=P from LDS). No __syncthreads anywhere.
__global__ __launch_bounds__(128) void k_attn(
    const u16* __restrict__ Q, const u16* __restrict__ K, const u16* __restrict__ Vt,
    const unsigned long long* __restrict__ padbits, u16* __restrict__ O) {
  __shared__ __align__(16) u16 Ps[64 * 72];

  const int qi = 31 - blockIdx.x;           // big tiles first
  const int bh = blockIdx.y;
  const int bI = bh >> 4, hI = bh & 15;
  const int q0 = qi * 64;
  const u16* Qg = Q + (size_t)bh * 2048 * 64;
  const u16* Kg = K + (size_t)bh * 2048 * 64;
  const u16* Vg = Vt + (size_t)bh * 64 * 2048;

  const int t = threadIdx.x, wv = t >> 6, ln = t & 63;
  const int lr = ln & 15, q4 = (ln >> 4) * 4, q8 = (ln >> 4) * 8;
  const int qbase = q0 + wv * 32;           // wave's 32 query columns
  const int qrow = wv * 32;                 // LDS row base

  // preload Q B-frags: bq[n][ks] (rows q, contiguous d)
  bf16x8 bq[2][2];
#pragma unroll
  for (int n = 0; n < 2; ++n)
#pragma unroll
    for (int ks = 0; ks < 2; ++ks)
      bq[n][ks] = *reinterpret_cast<const bf16x8*>(
          Qg + (size_t)(qbase + n * 16 + lr) * 64 + ks * 32 + q8);

  float mo[2] = {-1e30f, -1e30f}, lo[2] = {0.f, 0.f};
  f32x4 Oc[4][2] = {};  // O^T: [d-tile][q-tile], row=d=q4+r, col=q=lr

  for (int j = 0; j <= qi; ++j) {
    const int kb = j * 64;
    const unsigned long long pb = padbits[bI * 32 + j];

    // S^T = K Q^T : sc[m=s-tile][n=q-tile]
    f32x4 sc[4][2] = {};
#pragma unroll
    for (int ks = 0; ks < 2; ++ks) {
      bf16x8 ak[4];
#pragma unroll
      for (int m = 0; m < 4; ++m)
        ak[m] = *reinterpret_cast<const bf16x8*>(
            Kg + (size_t)(kb + m * 16 + lr) * 64 + ks * 32 + q8);
#pragma unroll
      for (int m = 0; m < 4; ++m)
#pragma unroll
        for (int n = 0; n < 2; ++n)
          sc[m][n] = __builtin_amdgcn_mfma_f32_16x16x32_bf16(ak[m], bq[n][ks], sc[m][n], 0, 0, 0);
    }

    // mask + online softmax; lane owns query column q = qbase + n*16 + lr
#pragma unroll
    for (int n = 0; n < 2; ++n) {
      const int qabs = qbase + n * 16 + lr;
      float vmax = -1e30f;
#pragma unroll
      for (int m = 0; m < 4; ++m)
#pragma unroll
        for (int r = 0; r < 4; ++r) {
          const int sl = m * 16 + q4 + r;          // key index within tile
          float v = sc[m][n][r] * 0.125f;
          const bool dead = (kb + sl > qabs) || ((pb >> sl) & 1ull);
          v = dead ? -1e30f : v;
          sc[m][n][r] = v;
          vmax = fmaxf(vmax, v);
        }
      vmax = fmaxf(vmax, __shfl_xor(vmax, 16, 64));
      vmax = fmaxf(vmax, __shfl_xor(vmax, 32, 64));
      const float mn = fmaxf(mo[n], vmax);
      const float al = __expf(mo[n] - mn);
      mo[n] = mn;
      float ps = 0.f;
#pragma unroll
      for (int m = 0; m < 4; ++m) {
        uint2 pk;
        float p0 = __expf(sc[m][n][0] - mn), p1 = __expf(sc[m][n][1] - mn);
        float p2 = __expf(sc[m][n][2] - mn), p3 = __expf(sc[m][n][3] - mn);
        ps += (p0 + p1) + (p2 + p3);
        pk.x = (uint32_t)f2bf(p0) | ((uint32_t)f2bf(p1) << 16);
        pk.y = (uint32_t)f2bf(p2) | ((uint32_t)f2bf(p3) << 16);
        *reinterpret_cast<uint2*>(Ps + (qrow + n * 16 + lr) * 72 + m * 16 + q4) = pk;
      }
      ps += __shfl_xor(ps, 16, 64);
      ps += __shfl_xor(ps, 32, 64);
      lo[n] = lo[n] * al + ps;
#pragma unroll
      for (int md = 0; md < 4; ++md) {
        Oc[md][n][0] *= al; Oc[md][n][1] *= al;
        Oc[md][n][2] *= al; Oc[md][n][3] *= al;
      }
    }

    // O^T += V^T P^T : A = Vt rows d (global), B = P rows q (LDS, same-wave rows)
#pragma unroll
    for (int ks = 0; ks < 2; ++ks) {
      bf16x8 av[4], bp[2];
#pragma unroll
      for (int md = 0; md < 4; ++md)
        av[md] = *reinterpret_cast<const bf16x8*>(
            Vg + (size_t)(md * 16 + lr) * 2048 + kb + ks * 32 + q8);
#pragma unroll
      for (int n = 0; n < 2; ++n)
        bp[n] = *reinterpret_cast<const bf16x8*>(Ps + (qrow + n * 16 + lr) * 72 + ks * 32 + q8);
#pragma unroll
      for (int md = 0; md < 4; ++md)
#pragma unroll
        for (int n = 0; n < 2; ++n)
          Oc[md][n] = __builtin_amdgcn_mfma_f32_16x16x32_bf16(av[md], bp[n], Oc[md][n], 0, 0, 0);
    }
  }

  // epilogue: O[token][h*64+d] = O^T[d][q] / l_q  (4 d-consecutive bf16 per store)
#pragma unroll
  for (int n = 0; n < 2; ++n) {
    const float inv = 1.f / lo[n];
    const int qabs = qbase + n * 16 + lr;
    const size_t base = ((size_t)(bI * 2048 + qabs)) * 1024 + hI * 64;
#pragma unroll
    for (int md = 0; md < 4; ++md) {
      uint2 pk;
      pk.x = (uint32_t)f2bf(Oc[md][n][0] * inv) | ((uint32_t)f2bf(Oc[md][n][1] * inv) << 16);
      pk.y = (uint32_t)f2bf(Oc[md][n][2] * inv) | ((uint32_t)f2bf(Oc[md][n][3] * inv) << 16);
      *reinterpret_cast<uint2*>(O + base + md * 16 + q4) = pk;
    }
  }
}

// ---------------- launch ----------------

extern "C" void kernel_launch(void* const* d_in, const int* in_sizes, int n_in,
                              void* d_out, int out_size, void* d_ws, size_t ws_size,
                              hipStream_t stream) {
  (void)in_sizes; (void)n_in; (void)out_size; (void)ws_size;
  const float* batch = (const float*)d_in[0];
  const int* ids     = (const int*)d_in[1];
  const float* W_Q   = (const float*)d_in[2];
  const float* W_K   = (const float*)d_in[3];
  const float* W_V   = (const float*)d_in[4];
  const float* b_Q   = (const float*)d_in[5];
  const float* b_K   = (const float*)d_in[6];
  const float* b_V   = (const float*)d_in[7];
  const float* W_O   = (const float*)d_in[8];
  const float* b_O   = (const float*)d_in[9];
  float* out = (float*)d_out;

  u16* ws = (u16*)d_ws;
  u16* Xbf   = ws;                       // 4096*1024
  u16* WqkvT = Xbf + 4096 * 1024;        // 3072*1024
  u16* WoT   = WqkvT + 3072 * 1024;      // 1024*1024
  u16* Qb    = WoT + 1024 * 1024;        // 4096*1024
  u16* Kb    = Qb + 4096 * 1024;
  u16* Vtb   = Kb + 4096 * 1024;         // transposed V [bh][64][2048]
  u16* Ob    = Xbf;                      // reuse X after k_qkv

  // padbits live in the tail of d_out (64 * 8B); k_attn reads them before k_out overwrites.
  unsigned long long* padbits =
      (unsigned long long*)((char*)d_out + (size_t)out_size * 4 - 512);

  k_padbits<<<16, 256, 0, stream>>>(ids, padbits);
  k_cast<<<4096, 256, 0, stream>>>(batch, Xbf);
  k_transpose4<<<dim3(32, 32, 4), dim3(32, 8), 0, stream>>>(W_Q, W_K, W_V, W_O, WqkvT, WoT);
  k_qkv<<<dim3(32, 24), 256, 0, stream>>>(Xbf, WqkvT, b_Q, b_K, b_V, Qb, Kb, Vtb);
  k_attn<<<dim3(32, 32), 128, 0, stream>>>(Qb, Kb, Vtb, padbits, Ob);
  k_out<<<dim3(32, 8), 256, 0, stream>>>(Ob, WoT, b_O, out);
}

// Round 4
// 247.449 us; speedup vs baseline: 1.2450x; 1.2450x over previous
//
#include <hip/hip_runtime.h>
#include <stdint.h>

// B=2, S=2048, H=1024, NH=16, DK=DV=64, M=4096.
// cast/transpose -> QKV gemm (V transposed) -> SPLIT-K flash attn -> merge -> out gemm.
// ws (u16 elems): X(4.19M) WqkvT(3.15M) WoT(1.05M) Q(4.19M) K(4.19M) Vt(4.19M) Opart(10.49M)
// Mpart/Lpart overlay the dead WqkvT region after k_qkv. Peak ~62.9 MB.
// padbits (64 x u64) in tail of d_out (written first, read by k_attn, overwritten by k_out).

typedef unsigned short u16;
typedef __attribute__((ext_vector_type(8))) __bf16 bf16x8;
typedef __attribute__((ext_vector_type(4))) float f32x4;

#define SCL 0.18033688011112042f  // 0.125 * log2(e)

__device__ __forceinline__ u16 f2bf(float f) {
  union { float f; uint32_t u; } v; v.f = f;
  uint32_t r = v.u + 0x7FFFu + ((v.u >> 16) & 1u);  // RNE
  return (u16)(r >> 16);
}

__device__ __forceinline__ void gl_lds16(const u16* g, u16* l) {
  auto gp = reinterpret_cast<const __attribute__((address_space(1))) uint32_t*>(
      reinterpret_cast<uintptr_t>(g));
  auto lp = reinterpret_cast<__attribute__((address_space(3))) uint32_t*>(
      reinterpret_cast<uintptr_t>(l));
  __builtin_amdgcn_global_load_lds(gp, lp, 16, 0, 0);
}

// ---------------- prologue ----------------

__global__ void k_cast(const float* __restrict__ src, u16* __restrict__ dst) {
  int idx = (blockIdx.x * 256 + threadIdx.x) * 4;
  const float4 v = *reinterpret_cast<const float4*>(src + idx);
  uint2 o;
  o.x = (uint32_t)f2bf(v.x) | ((uint32_t)f2bf(v.y) << 16);
  o.y = (uint32_t)f2bf(v.z) | ((uint32_t)f2bf(v.w) << 16);
  *reinterpret_cast<uint2*>(dst + idx) = o;
}

__global__ void k_transpose4(const float* __restrict__ s0, const float* __restrict__ s1,
                             const float* __restrict__ s2, const float* __restrict__ s3,
                             u16* __restrict__ dqkv, u16* __restrict__ dwo) {
  __shared__ float tile[32][33];
  int z = blockIdx.z;
  const float* src = z == 0 ? s0 : (z == 1 ? s1 : (z == 2 ? s2 : s3));
  u16* dst = z < 3 ? dqkv + (size_t)z * 1024 * 1024 : dwo;
  int c0 = blockIdx.x * 32, r0 = blockIdx.y * 32;
  int tx = threadIdx.x, ty = threadIdx.y;  // (32,8)
#pragma unroll
  for (int i = 0; i < 4; ++i)
    tile[ty + i * 8][tx] = src[(size_t)(r0 + ty + i * 8) * 1024 + c0 + tx];
  __syncthreads();
#pragma unroll
  for (int i = 0; i < 4; ++i)
    dst[(size_t)(c0 + ty + i * 8) * 1024 + r0 + tx] = f2bf(tile[tx][ty + i * 8]);
}

__global__ void k_padbits(const int* __restrict__ ids, unsigned long long* __restrict__ pb) {
  int idx = blockIdx.x * 4 + (threadIdx.x >> 6);
  int ln = threadIdx.x & 63;
  int b = idx >> 5, j = idx & 31;
  unsigned long long m = __ballot(ids[b * 2048 + j * 64 + ln] == 0);
  if (ln == 0) pb[idx] = m;
}

// ---------------- GEMM core (m97 structure) ----------------

__device__ __forceinline__ void gemm_tile_acc(
    const u16* __restrict__ A, const u16* __restrict__ Bt, int K,
    int tm, int tn, u16* As, u16* Bs, f32x4 acc[4][4]) {
  const int t = threadIdx.x, wv = t >> 6, ln = t & 63;
  const int wr = (wv & 1) * 64, wc = (wv >> 1) * 64;
  const int lr = ln & 15, q8 = (ln >> 4) * 8;
  const int srow = ln >> 2, scol = (ln & 3) * 8;

  for (int k0 = 0; k0 < K; k0 += 32) {
#pragma unroll
    for (int i = 0; i < 2; ++i) {
      int c = wv + i * 4;
      gl_lds16(A + (size_t)(tm + c * 16 + srow) * K + k0 + scol, As + c * 512 + ln * 8);
      gl_lds16(Bt + (size_t)(tn + c * 16 + srow) * K + k0 + scol, Bs + c * 512 + ln * 8);
    }
    __syncthreads();
    bf16x8 av[4], bv[4];
#pragma unroll
    for (int m = 0; m < 4; ++m)
      av[m] = *reinterpret_cast<const bf16x8*>(As + (wr + m * 16 + lr) * 32 + q8);
#pragma unroll
    for (int n = 0; n < 4; ++n)
      bv[n] = *reinterpret_cast<const bf16x8*>(Bs + (wc + n * 16 + lr) * 32 + q8);
#pragma unroll
    for (int m = 0; m < 4; ++m)
#pragma unroll
      for (int n = 0; n < 4; ++n)
        acc[m][n] = __builtin_amdgcn_mfma_f32_16x16x32_bf16(av[m], bv[n], acc[m][n], 0, 0, 0);
    __syncthreads();
  }
}

// QKV projection. Q,K -> [bh][s][64]; V -> TRANSPOSED [bh][64][2048]
__global__ __launch_bounds__(256) void k_qkv(
    const u16* __restrict__ X, const u16* __restrict__ Wt,
    const float* __restrict__ bQ, const float* __restrict__ bK, const float* __restrict__ bV,
    u16* __restrict__ Q, u16* __restrict__ Kd, u16* __restrict__ V) {
  __shared__ __align__(16) u16 As[128 * 32];
  __shared__ __align__(16) u16 Bs[128 * 32];
  f32x4 acc[4][4] = {};
  const int tm = blockIdx.x * 128, tn = blockIdx.y * 128;
  gemm_tile_acc(X, Wt, 1024, tm, tn, As, Bs, acc);

  const int t = threadIdx.x, wv = t >> 6, ln = t & 63;
  const int wr = (wv & 1) * 64, wc = (wv >> 1) * 64;
  const int lr = ln & 15, q4 = (ln >> 4) * 4;
  const int which = tn >> 10;

  if (which < 2) {
    u16* dst = which == 0 ? Q : Kd;
    const float* bias = which == 0 ? bQ : bK;
#pragma unroll
    for (int n = 0; n < 4; ++n) {
      int gc = tn + wc + n * 16 + lr;
      int f = gc & 1023;
      float bb = bias[f];
      int h = f >> 6, dd = f & 63;
#pragma unroll
      for (int m = 0; m < 4; ++m)
#pragma unroll
        for (int r = 0; r < 4; ++r) {
          int gr = tm + wr + m * 16 + q4 + r;
          int b = gr >> 11, s = gr & 2047;
          dst[((size_t)((b * 16 + h) * 2048 + s)) * 64 + dd] = f2bf(acc[m][n][r] + bb);
        }
    }
  } else {
#pragma unroll
    for (int n = 0; n < 4; ++n) {
      int gc = tn + wc + n * 16 + lr;
      int f = gc & 1023;
      float bb = bV[f];
      int h = f >> 6, dd = f & 63;
#pragma unroll
      for (int m = 0; m < 4; ++m) {
        int gr0 = tm + wr + m * 16 + q4;
        int b = gr0 >> 11, s0 = gr0 & 2047;
        uint2 pk;
        pk.x = (uint32_t)f2bf(acc[m][n][0] + bb) | ((uint32_t)f2bf(acc[m][n][1] + bb) << 16);
        pk.y = (uint32_t)f2bf(acc[m][n][2] + bb) | ((uint32_t)f2bf(acc[m][n][3] + bb) << 16);
        *reinterpret_cast<uint2*>(V + ((size_t)((b * 16 + h) * 64 + dd)) * 2048 + s0) = pk;
      }
    }
  }
}

// Output projection -> fp32 out
__global__ __launch_bounds__(256) void k_out(
    const u16* __restrict__ O, const u16* __restrict__ WoT,
    const float* __restrict__ bO, float* __restrict__ out) {
  __shared__ __align__(16) u16 As[128 * 32];
  __shared__ __align__(16) u16 Bs[128 * 32];
  f32x4 acc[4][4] = {};
  const int tm = blockIdx.x * 128, tn = blockIdx.y * 128;
  gemm_tile_acc(O, WoT, 1024, tm, tn, As, Bs, acc);

  const int t = threadIdx.x, wv = t >> 6, ln = t & 63;
  const int wr = (wv & 1) * 64, wc = (wv >> 1) * 64;
  const int lr = ln & 15, q4 = (ln >> 4) * 4;
#pragma unroll
  for (int n = 0; n < 4; ++n) {
    int gc = tn + wc + n * 16 + lr;
    float bb = bO[gc];
#pragma unroll
    for (int m = 0; m < 4; ++m)
#pragma unroll
      for (int r = 0; r < 4; ++r) {
        int gr = tm + wr + m * 16 + q4 + r;
        out[(size_t)gr * 1024 + gc] = acc[m][n][r] + bb;
      }
  }
}

// ---------------- split-K flash attention ----------------
// 2560 items: id = w*32 + bh with w=79-(id>>5) big-first; w -> (qi, chunk c) bands:
//   w<8: qi=w,c=0 | 8..23: qi=8+(w-8)/2 | 24..47: qi=16+(w-24)/3 | 48..79: qi=24+(w-48)/4
// Block 128 thr = 2 independent waves x 32 q. Chunk = up to 8 k-tiles (512 keys).
// Writes per-chunk normalized O' (bf16) + raw m,l (fp32) partials; k_merge combines.
__global__ __launch_bounds__(128) void k_attn(
    const u16* __restrict__ Q, const u16* __restrict__ K, const u16* __restrict__ Vt,
    const unsigned long long* __restrict__ padbits,
    u16* __restrict__ Opart, float* __restrict__ Mpart, float* __restrict__ Lpart) {
  __shared__ __align__(16) u16 Ps[64 * 72];

  const int id = blockIdx.x;
  const int bh = id & 31;
  const int w = 79 - (id >> 5);  // big chunks (high qi) dispatched first
  int qi, c;
  if (w < 8)       { qi = w;                c = 0; }
  else if (w < 24) { qi = 8 + ((w - 8) >> 1);  c = (w - 8) & 1; }
  else if (w < 48) { qi = 16 + (w - 24) / 3;   c = (w - 24) % 3; }
  else             { qi = 24 + ((w - 48) >> 2); c = (w - 48) & 3; }
  const int jts = c * 8;
  const int jte = min(qi + 1, jts + 8);
  const int slot = bh * 80 + w;

  const int bI = bh >> 4;
  const int q0 = qi * 64;
  const u16* Qg = Q + (size_t)bh * 2048 * 64;
  const u16* Kg = K + (size_t)bh * 2048 * 64;
  const u16* Vg = Vt + (size_t)bh * 64 * 2048;

  const int t = threadIdx.x, wv = t >> 6, ln = t & 63;
  const int lr = ln & 15, q4 = (ln >> 4) * 4, q8 = (ln >> 4) * 8;
  const int qbase = q0 + wv * 32;
  const int qrow = wv * 32;

  bf16x8 bq[2][2];
#pragma unroll
  for (int n = 0; n < 2; ++n)
#pragma unroll
    for (int ks = 0; ks < 2; ++ks)
      bq[n][ks] = *reinterpret_cast<const bf16x8*>(
          Qg + (size_t)(qbase + n * 16 + lr) * 64 + ks * 32 + q8);

  float mo[2] = {-1e30f, -1e30f}, lo[2] = {0.f, 0.f};
  f32x4 Oc[4][2] = {};

  for (int j = jts; j < jte; ++j) {
    const int kb = j * 64;
    const unsigned long long pb = padbits[bI * 32 + j];
    const bool masked = (kb + 63 > qbase) || (pb != 0);

    // S^T = K Q^T (raw scores; 1/sqrt(d) folded into exp2 scale)
    f32x4 sc[4][2] = {};
#pragma unroll
    for (int ks = 0; ks < 2; ++ks) {
      bf16x8 ak[4];
#pragma unroll
      for (int m = 0; m < 4; ++m)
        ak[m] = *reinterpret_cast<const bf16x8*>(
            Kg + (size_t)(kb + m * 16 + lr) * 64 + ks * 32 + q8);
#pragma unroll
      for (int m = 0; m < 4; ++m)
#pragma unroll
        for (int n = 0; n < 2; ++n)
          sc[m][n] = __builtin_amdgcn_mfma_f32_16x16x32_bf16(ak[m], bq[n][ks], sc[m][n], 0, 0, 0);
    }

#pragma unroll
    for (int n = 0; n < 2; ++n) {
      const int qabs = qbase + n * 16 + lr;
      float vmax = -1e30f;
      if (masked) {
#pragma unroll
        for (int m = 0; m < 4; ++m)
#pragma unroll
          for (int r = 0; r < 4; ++r) {
            const int sl = m * 16 + q4 + r;
            float v = sc[m][n][r];
            const bool dead = (kb + sl > qabs) || ((pb >> sl) & 1ull);
            v = dead ? -1e30f : v;
            sc[m][n][r] = v;
            vmax = fmaxf(vmax, v);
          }
      } else {
#pragma unroll
        for (int m = 0; m < 4; ++m)
#pragma unroll
          for (int r = 0; r < 4; ++r) vmax = fmaxf(vmax, sc[m][n][r]);
      }
      vmax = fmaxf(vmax, __shfl_xor(vmax, 16, 64));
      vmax = fmaxf(vmax, __shfl_xor(vmax, 32, 64));
      const float mn = fmaxf(mo[n], vmax);
      const float al = exp2f((mo[n] - mn) * SCL);
      const float mnC = mn * SCL;
      mo[n] = mn;
      float ps = 0.f;
#pragma unroll
      for (int m = 0; m < 4; ++m) {
        uint2 pk;
        float p0 = exp2f(__builtin_fmaf(sc[m][n][0], SCL, -mnC));
        float p1 = exp2f(__builtin_fmaf(sc[m][n][1], SCL, -mnC));
        float p2 = exp2f(__builtin_fmaf(sc[m][n][2], SCL, -mnC));
        float p3 = exp2f(__builtin_fmaf(sc[m][n][3], SCL, -mnC));
        ps += (p0 + p1) + (p2 + p3);
        pk.x = (uint32_t)f2bf(p0) | ((uint32_t)f2bf(p1) << 16);
        pk.y = (uint32_t)f2bf(p2) | ((uint32_t)f2bf(p3) << 16);
        *reinterpret_cast<uint2*>(Ps + (qrow + n * 16 + lr) * 72 + m * 16 + q4) = pk;
      }
      ps += __shfl_xor(ps, 16, 64);
      ps += __shfl_xor(ps, 32, 64);
      lo[n] = lo[n] * al + ps;
#pragma unroll
      for (int md = 0; md < 4; ++md) {
        Oc[md][n][0] *= al; Oc[md][n][1] *= al;
        Oc[md][n][2] *= al; Oc[md][n][3] *= al;
      }
    }

    // O^T += V^T P^T
#pragma unroll
    for (int ks = 0; ks < 2; ++ks) {
      bf16x8 av[4], bp[2];
#pragma unroll
      for (int md = 0; md < 4; ++md)
        av[md] = *reinterpret_cast<const bf16x8*>(
            Vg + (size_t)(md * 16 + lr) * 2048 + kb + ks * 32 + q8);
#pragma unroll
      for (int n = 0; n < 2; ++n)
        bp[n] = *reinterpret_cast<const bf16x8*>(Ps + (qrow + n * 16 + lr) * 72 + ks * 32 + q8);
#pragma unroll
      for (int md = 0; md < 4; ++md)
#pragma unroll
        for (int n = 0; n < 2; ++n)
          Oc[md][n] = __builtin_amdgcn_mfma_f32_16x16x32_bf16(av[md], bp[n], Oc[md][n], 0, 0, 0);
    }
  }

  // partial epilogue: O'[q][d] = O^T/l (bf16), m/l raw fp32
  const size_t obase = (size_t)slot * 4096;
#pragma unroll
  for (int n = 0; n < 2; ++n) {
    const float inv = 1.f / lo[n];
    const int qlocal = qrow + n * 16 + lr;
#pragma unroll
    for (int md = 0; md < 4; ++md) {
      uint2 pk;
      pk.x = (uint32_t)f2bf(Oc[md][n][0] * inv) | ((uint32_t)f2bf(Oc[md][n][1] * inv) << 16);
      pk.y = (uint32_t)f2bf(Oc[md][n][2] * inv) | ((uint32_t)f2bf(Oc[md][n][3] * inv) << 16);
      *reinterpret_cast<uint2*>(Opart + obase + (size_t)qlocal * 64 + md * 16 + q4) = pk;
    }
    if (ln < 16) {
      Mpart[slot * 64 + qlocal] = mo[n];
      Lpart[slot * 64 + qlocal] = lo[n];
    }
  }
}

// merge partials: block per (bh, qi); thread t: q = t>>2, 16 d's at (t&3)*16
__global__ __launch_bounds__(256) void k_merge(
    const u16* __restrict__ Opart, const float* __restrict__ Mpart,
    const float* __restrict__ Lpart, u16* __restrict__ O) {
  const int bh = blockIdx.x >> 5, qi = blockIdx.x & 31;
  const int nc = (qi >> 3) + 1;
  const int band = qi >> 3;
  const int pre = (band == 0 ? 0 : band == 1 ? 8 : band == 2 ? 24 : 48) + (qi & 7) * (band + 1);
  const int slot0 = bh * 80 + pre;

  const int t = threadIdx.x;
  const int q = t >> 2, ds = (t & 3) * 16;

  float mc[4], lc[4];
  for (int cI = 0; cI < nc; ++cI) {
    mc[cI] = Mpart[(slot0 + cI) * 64 + q];
    lc[cI] = Lpart[(slot0 + cI) * 64 + q];
  }
  float M = mc[0];
  for (int cI = 1; cI < nc; ++cI) M = fmaxf(M, mc[cI]);
  float wc[4], wsum = 0.f;
  for (int cI = 0; cI < nc; ++cI) {
    wc[cI] = lc[cI] * exp2f((mc[cI] - M) * SCL);
    wsum += wc[cI];
  }
  const float inv = 1.f / wsum;

  float acc[16];
#pragma unroll
  for (int e = 0; e < 16; ++e) acc[e] = 0.f;
  for (int cI = 0; cI < nc; ++cI) {
    const u16* src = Opart + (size_t)(slot0 + cI) * 4096 + q * 64 + ds;
    uint4 a = *reinterpret_cast<const uint4*>(src);
    uint4 b = *reinterpret_cast<const uint4*>(src + 8);
    uint32_t uu[8] = {a.x, a.y, a.z, a.w, b.x, b.y, b.z, b.w};
    const float wci = wc[cI];
#pragma unroll
    for (int p = 0; p < 8; ++p) {
      acc[2 * p]     += wci * __uint_as_float(uu[p] << 16);
      acc[2 * p + 1] += wci * __uint_as_float(uu[p] & 0xFFFF0000u);
    }
  }

  const int bI = bh >> 4, hI = bh & 15;
  const size_t row = (size_t)(bI * 2048 + qi * 64 + q);
  u16* dst = O + row * 1024 + hI * 64 + ds;
  uint32_t op[8];
#pragma unroll
  for (int p = 0; p < 8; ++p)
    op[p] = (uint32_t)f2bf(acc[2 * p] * inv) | ((uint32_t)f2bf(acc[2 * p + 1] * inv) << 16);
  *reinterpret_cast<uint4*>(dst) = *reinterpret_cast<const uint4*>(&op[0]);
  *reinterpret_cast<uint4*>(dst + 8) = *reinterpret_cast<const uint4*>(&op[4]);
}

// ---------------- launch ----------------

extern "C" void kernel_launch(void* const* d_in, const int* in_sizes, int n_in,
                              void* d_out, int out_size, void* d_ws, size_t ws_size,
                              hipStream_t stream) {
  (void)in_sizes; (void)n_in; (void)out_size; (void)ws_size;
  const float* batch = (const float*)d_in[0];
  const int* ids     = (const int*)d_in[1];
  const float* W_Q   = (const float*)d_in[2];
  const float* W_K   = (const float*)d_in[3];
  const float* W_V   = (const float*)d_in[4];
  const float* b_Q   = (const float*)d_in[5];
  const float* b_K   = (const float*)d_in[6];
  const float* b_V   = (const float*)d_in[7];
  const float* W_O   = (const float*)d_in[8];
  const float* b_O   = (const float*)d_in[9];
  float* out = (float*)d_out;

  u16* ws = (u16*)d_ws;
  u16* Xbf   = ws;                        // 4,194,304
  u16* WqkvT = Xbf + 4194304;             // 3,145,728 (dead after k_qkv)
  u16* WoT   = WqkvT + 3145728;           // 1,048,576
  u16* Qb    = WoT + 1048576;             // 4,194,304
  u16* Kb    = Qb + 4194304;              // 4,194,304
  u16* Vtb   = Kb + 4194304;              // 4,194,304
  u16* Opart = Vtb + 4194304;             // 2560*4096 = 10,485,760
  // M/L partials overlay the dead WqkvT region (k_attn writes, k_merge reads)
  float* Mpart = (float*)WqkvT;               // 163,840 f32
  float* Lpart = Mpart + 163840;              // 163,840 f32
  u16* Ob    = Xbf;                       // reuse X after k_qkv

  unsigned long long* padbits =
      (unsigned long long*)((char*)d_out + (size_t)out_size * 4 - 512);

  k_padbits<<<16, 256, 0, stream>>>(ids, padbits);
  k_cast<<<4096, 256, 0, stream>>>(batch, Xbf);
  k_transpose4<<<dim3(32, 32, 4), dim3(32, 8), 0, stream>>>(W_Q, W_K, W_V, W_O, WqkvT, WoT);
  k_qkv<<<dim3(32, 24), 256, 0, stream>>>(Xbf, WqkvT, b_Q, b_K, b_V, Qb, Kb, Vtb);
  k_attn<<<2560, 128, 0, stream>>>(Qb, Kb, Vtb, padbits, Opart, Mpart, Lpart);
  k_merge<<<1024, 256, 0, stream>>>(Opart, Mpart, Lpart, Ob);
  k_out<<<dim3(32, 8), 256, 0, stream>>>(Ob, WoT, b_O, out);
}

// Round 5
// 243.739 us; speedup vs baseline: 1.2639x; 1.0152x over previous
//
#include <hip/hip_runtime.h>
#include <stdint.h>

// B=2, S=2048, H=1024, NH=16, DK=DV=64, M=4096.
// prologue(fused cast/transpose/padbits) -> QKV gemm (V transposed) -> split-K flash attn
// (K/V staged via LDS) -> merge -> out gemm.
// ws (u16 elems): X(4.19M) WqkvT(3.15M) WoT(1.05M) Q(4.19M) K(4.19M) Vt(4.19M) Opart(10.49M)
// Mpart/Lpart overlay the dead WqkvT region after k_qkv. Peak ~62.9 MB.
// padbits (64 x u64) in tail of d_out (written first, read by k_attn, overwritten by k_out).

typedef unsigned short u16;
typedef __attribute__((ext_vector_type(8))) __bf16 bf16x8;
typedef __attribute__((ext_vector_type(4))) float f32x4;

#define SCL 0.18033688011112042f  // 0.125 * log2(e)

__device__ __forceinline__ u16 f2bf(float f) {
  union { float f; uint32_t u; } v; v.f = f;
  uint32_t r = v.u + 0x7FFFu + ((v.u >> 16) & 1u);  // RNE
  return (u16)(r >> 16);
}

__device__ __forceinline__ void gl_lds16(const u16* g, u16* l) {
  auto gp = reinterpret_cast<const __attribute__((address_space(1))) uint32_t*>(
      reinterpret_cast<uintptr_t>(g));
  auto lp = reinterpret_cast<__attribute__((address_space(3))) uint32_t*>(
      reinterpret_cast<uintptr_t>(l));
  __builtin_amdgcn_global_load_lds(gp, lp, 16, 0, 0);
}

// ---------------- fused prologue ----------------
// blocks 0..4095: cast batch->bf16; 4096..8191: 4x transpose 1024x1024; 8192..8207: padbits
__global__ void k_prologue(const float* __restrict__ batch, const int* __restrict__ ids,
                           const float* __restrict__ W_Q, const float* __restrict__ W_K,
                           const float* __restrict__ W_V, const float* __restrict__ W_O,
                           u16* __restrict__ Xbf, u16* __restrict__ dqkv, u16* __restrict__ dwo,
                           unsigned long long* __restrict__ pb) {
  __shared__ float tile[32][33];
  const int bx = blockIdx.x, t = threadIdx.x;
  if (bx < 4096) {
    int idx = (bx * 256 + t) * 4;
    const float4 v = *reinterpret_cast<const float4*>(batch + idx);
    uint2 o;
    o.x = (uint32_t)f2bf(v.x) | ((uint32_t)f2bf(v.y) << 16);
    o.y = (uint32_t)f2bf(v.z) | ((uint32_t)f2bf(v.w) << 16);
    *reinterpret_cast<uint2*>(Xbf + idx) = o;
  } else if (bx < 8192) {
    int b2 = bx - 4096;
    int z = b2 >> 10;
    b2 &= 1023;
    const float* src = z == 0 ? W_Q : (z == 1 ? W_K : (z == 2 ? W_V : W_O));
    u16* dst = z < 3 ? dqkv + (size_t)z * 1024 * 1024 : dwo;
    int c0 = (b2 & 31) * 32, r0 = (b2 >> 5) * 32;
    int tx = t & 31, ty = t >> 5;  // (32,8)
#pragma unroll
    for (int i = 0; i < 4; ++i)
      tile[ty + i * 8][tx] = src[(size_t)(r0 + ty + i * 8) * 1024 + c0 + tx];
    __syncthreads();
#pragma unroll
    for (int i = 0; i < 4; ++i)
      dst[(size_t)(c0 + ty + i * 8) * 1024 + r0 + tx] = f2bf(tile[tx][ty + i * 8]);
  } else {
    int idx = (bx - 8192) * 4 + (t >> 6);
    int ln = t & 63;
    int b = idx >> 5, j = idx & 31;
    unsigned long long m = __ballot(ids[b * 2048 + j * 64 + ln] == 0);
    if (ln == 0) pb[idx] = m;
  }
}

// ---------------- GEMM core (m97 structure) ----------------

__device__ __forceinline__ void gemm_tile_acc(
    const u16* __restrict__ A, const u16* __restrict__ Bt, int K,
    int tm, int tn, u16* As, u16* Bs, f32x4 acc[4][4]) {
  const int t = threadIdx.x, wv = t >> 6, ln = t & 63;
  const int wr = (wv & 1) * 64, wc = (wv >> 1) * 64;
  const int lr = ln & 15, q8 = (ln >> 4) * 8;
  const int srow = ln >> 2, scol = (ln & 3) * 8;

  for (int k0 = 0; k0 < K; k0 += 32) {
#pragma unroll
    for (int i = 0; i < 2; ++i) {
      int c = wv + i * 4;
      gl_lds16(A + (size_t)(tm + c * 16 + srow) * K + k0 + scol, As + c * 512 + ln * 8);
      gl_lds16(Bt + (size_t)(tn + c * 16 + srow) * K + k0 + scol, Bs + c * 512 + ln * 8);
    }
    __syncthreads();
    bf16x8 av[4], bv[4];
#pragma unroll
    for (int m = 0; m < 4; ++m)
      av[m] = *reinterpret_cast<const bf16x8*>(As + (wr + m * 16 + lr) * 32 + q8);
#pragma unroll
    for (int n = 0; n < 4; ++n)
      bv[n] = *reinterpret_cast<const bf16x8*>(Bs + (wc + n * 16 + lr) * 32 + q8);
#pragma unroll
    for (int m = 0; m < 4; ++m)
#pragma unroll
      for (int n = 0; n < 4; ++n)
        acc[m][n] = __builtin_amdgcn_mfma_f32_16x16x32_bf16(av[m], bv[n], acc[m][n], 0, 0, 0);
    __syncthreads();
  }
}

// QKV projection. Q,K -> [bh][s][64]; V -> TRANSPOSED [bh][64][2048]
__global__ __launch_bounds__(256) void k_qkv(
    const u16* __restrict__ X, const u16* __restrict__ Wt,
    const float* __restrict__ bQ, const float* __restrict__ bK, const float* __restrict__ bV,
    u16* __restrict__ Q, u16* __restrict__ Kd, u16* __restrict__ V) {
  __shared__ __align__(16) u16 As[128 * 32];
  __shared__ __align__(16) u16 Bs[128 * 32];
  f32x4 acc[4][4] = {};
  const int tm = blockIdx.x * 128, tn = blockIdx.y * 128;
  gemm_tile_acc(X, Wt, 1024, tm, tn, As, Bs, acc);

  const int t = threadIdx.x, wv = t >> 6, ln = t & 63;
  const int wr = (wv & 1) * 64, wc = (wv >> 1) * 64;
  const int lr = ln & 15, q4 = (ln >> 4) * 4;
  const int which = tn >> 10;

  if (which < 2) {
    u16* dst = which == 0 ? Q : Kd;
    const float* bias = which == 0 ? bQ : bK;
#pragma unroll
    for (int n = 0; n < 4; ++n) {
      int gc = tn + wc + n * 16 + lr;
      int f = gc & 1023;
      float bb = bias[f];
      int h = f >> 6, dd = f & 63;
#pragma unroll
      for (int m = 0; m < 4; ++m)
#pragma unroll
        for (int r = 0; r < 4; ++r) {
          int gr = tm + wr + m * 16 + q4 + r;
          int b = gr >> 11, s = gr & 2047;
          dst[((size_t)((b * 16 + h) * 2048 + s)) * 64 + dd] = f2bf(acc[m][n][r] + bb);
        }
    }
  } else {
#pragma unroll
    for (int n = 0; n < 4; ++n) {
      int gc = tn + wc + n * 16 + lr;
      int f = gc & 1023;
      float bb = bV[f];
      int h = f >> 6, dd = f & 63;
#pragma unroll
      for (int m = 0; m < 4; ++m) {
        int gr0 = tm + wr + m * 16 + q4;
        int b = gr0 >> 11, s0 = gr0 & 2047;
        uint2 pk;
        pk.x = (uint32_t)f2bf(acc[m][n][0] + bb) | ((uint32_t)f2bf(acc[m][n][1] + bb) << 16);
        pk.y = (uint32_t)f2bf(acc[m][n][2] + bb) | ((uint32_t)f2bf(acc[m][n][3] + bb) << 16);
        *reinterpret_cast<uint2*>(V + ((size_t)((b * 16 + h) * 64 + dd)) * 2048 + s0) = pk;
      }
    }
  }
}

// Output projection -> fp32 out
__global__ __launch_bounds__(256) void k_out(
    const u16* __restrict__ O, const u16* __restrict__ WoT,
    const float* __restrict__ bO, float* __restrict__ out) {
  __shared__ __align__(16) u16 As[128 * 32];
  __shared__ __align__(16) u16 Bs[128 * 32];
  f32x4 acc[4][4] = {};
  const int tm = blockIdx.x * 128, tn = blockIdx.y * 128;
  gemm_tile_acc(O, WoT, 1024, tm, tn, As, Bs, acc);

  const int t = threadIdx.x, wv = t >> 6, ln = t & 63;
  const int wr = (wv & 1) * 64, wc = (wv >> 1) * 64;
  const int lr = ln & 15, q4 = (ln >> 4) * 4;
#pragma unroll
  for (int n = 0; n < 4; ++n) {
    int gc = tn + wc + n * 16 + lr;
    float bb = bO[gc];
#pragma unroll
    for (int m = 0; m < 4; ++m)
#pragma unroll
      for (int r = 0; r < 4; ++r) {
        int gr = tm + wr + m * 16 + q4 + r;
        out[(size_t)gr * 1024 + gc] = acc[m][n][r] + bb;
      }
  }
}

// ---------------- split-K flash attention (LDS-staged K/V) ----------------
// 2560 items: id = w*32 + bh, w = 79-(id>>5) big-first; w -> (qi, chunk c) bands:
//   w<8: qi=w,c=0 | 8..23: qi=8+(w-8)/2 | 24..47: qi=16+(w-24)/3 | 48..79: qi=24+(w-48)/4
// Block 128 thr = 2 waves x 32 q. Chunk <= 8 k-tiles (512 keys). Per tile: wave0 stages
// K (two 32-col halves, m97 banking), wave1 stages V; B1; frags from LDS; B2; async
// prefetch next tile; softmax (perm-pack P to LDS); PV. Partials merged by k_merge.
__global__ __launch_bounds__(128) void k_attn(
    const u16* __restrict__ Q, const u16* __restrict__ K, const u16* __restrict__ Vt,
    const unsigned long long* __restrict__ padbits,
    u16* __restrict__ Opart, float* __restrict__ Mpart, float* __restrict__ Lpart) {
  __shared__ __align__(16) u16 Ks0[2048], Ks1[2048], Vs0[2048], Vs1[2048];
  __shared__ __align__(16) u16 Ps[64 * 72];

  const int id = blockIdx.x;
  const int bh = id & 31;
  const int w = 79 - (id >> 5);
  int qi, c;
  if (w < 8)       { qi = w;                   c = 0; }
  else if (w < 24) { qi = 8 + ((w - 8) >> 1);  c = (w - 8) & 1; }
  else if (w < 48) { qi = 16 + (w - 24) / 3;   c = (w - 24) % 3; }
  else             { qi = 24 + ((w - 48) >> 2); c = (w - 48) & 3; }
  const int jts = c * 8;
  const int jte = min(qi + 1, jts + 8);
  const int slot = bh * 80 + w;

  const int bI = bh >> 4;
  const int q0 = qi * 64;
  const u16* Qg = Q + (size_t)bh * 2048 * 64;
  const u16* Kg = K + (size_t)bh * 2048 * 64;
  const u16* Vg = Vt + (size_t)bh * 64 * 2048;

  const int t = threadIdx.x, wv = t >> 6, ln = t & 63;
  const int lr = ln & 15, q4 = (ln >> 4) * 4, q8 = (ln >> 4) * 8;
  const int qbase = q0 + wv * 32;
  const int qrow = wv * 32;
  const int srow = ln >> 2, scol = (ln & 3) * 8;

  bf16x8 bq[2][2];
#pragma unroll
  for (int n = 0; n < 2; ++n)
#pragma unroll
    for (int ks = 0; ks < 2; ++ks)
      bq[n][ks] = *reinterpret_cast<const bf16x8*>(
          Qg + (size_t)(qbase + n * 16 + lr) * 64 + ks * 32 + q8);

  float mo[2] = {-1e30f, -1e30f}, lo[2] = {0.f, 0.f};
  f32x4 Oc[4][2] = {};

  auto stage = [&](int kb) {
    if (wv == 0) {
#pragma unroll
      for (int cc = 0; cc < 4; ++cc) {
        gl_lds16(Kg + (size_t)(kb + cc * 16 + srow) * 64 + scol, Ks0 + cc * 512 + ln * 8);
        gl_lds16(Kg + (size_t)(kb + cc * 16 + srow) * 64 + 32 + scol, Ks1 + cc * 512 + ln * 8);
      }
    } else {
#pragma unroll
      for (int cc = 0; cc < 4; ++cc) {
        gl_lds16(Vg + (size_t)(cc * 16 + srow) * 2048 + kb + scol, Vs0 + cc * 512 + ln * 8);
        gl_lds16(Vg + (size_t)(cc * 16 + srow) * 2048 + kb + 32 + scol, Vs1 + cc * 512 + ln * 8);
      }
    }
  };
  stage(jts * 64);

  for (int j = jts; j < jte; ++j) {
    const int kb = j * 64;
    const unsigned long long pb = padbits[bI * 32 + j];
    const bool masked = (kb + 63 > qbase) || (pb != 0);
    __syncthreads();  // B1: staging of tile j complete

    // S^T = K Q^T from LDS frags
    f32x4 sc[4][2] = {};
    {
      bf16x8 ak0[4], ak1[4];
#pragma unroll
      for (int m = 0; m < 4; ++m) {
        ak0[m] = *reinterpret_cast<const bf16x8*>(Ks0 + (m * 16 + lr) * 32 + q8);
        ak1[m] = *reinterpret_cast<const bf16x8*>(Ks1 + (m * 16 + lr) * 32 + q8);
      }
#pragma unroll
      for (int m = 0; m < 4; ++m)
#pragma unroll
        for (int n = 0; n < 2; ++n) {
          sc[m][n] = __builtin_amdgcn_mfma_f32_16x16x32_bf16(ak0[m], bq[n][0], sc[m][n], 0, 0, 0);
          sc[m][n] = __builtin_amdgcn_mfma_f32_16x16x32_bf16(ak1[m], bq[n][1], sc[m][n], 0, 0, 0);
        }
    }
    // V frags now (before B2 / softmax)
    bf16x8 av0[4], av1[4];
#pragma unroll
    for (int md = 0; md < 4; ++md) {
      av0[md] = *reinterpret_cast<const bf16x8*>(Vs0 + (md * 16 + lr) * 32 + q8);
      av1[md] = *reinterpret_cast<const bf16x8*>(Vs1 + (md * 16 + lr) * 32 + q8);
    }
    __syncthreads();  // B2: all frag reads done
    if (j + 1 < jte) stage(kb + 64);  // async prefetch overlaps softmax

    // mask + online softmax; lane owns query column q = qbase + n*16 + lr
#pragma unroll
    for (int n = 0; n < 2; ++n) {
      const int qabs = qbase + n * 16 + lr;
      float vmax = -1e30f;
      if (masked) {
#pragma unroll
        for (int m = 0; m < 4; ++m)
#pragma unroll
          for (int r = 0; r < 4; ++r) {
            const int sl = m * 16 + q4 + r;
            float v = sc[m][n][r];
            const bool dead = (kb + sl > qabs) || ((pb >> sl) & 1ull);
            v = dead ? -1e30f : v;
            sc[m][n][r] = v;
            vmax = fmaxf(vmax, v);
          }
      } else {
#pragma unroll
        for (int m = 0; m < 4; ++m)
#pragma unroll
          for (int r = 0; r < 4; ++r) vmax = fmaxf(vmax, sc[m][n][r]);
      }
      vmax = fmaxf(vmax, __shfl_xor(vmax, 16, 64));
      vmax = fmaxf(vmax, __shfl_xor(vmax, 32, 64));
      const float mn = fmaxf(mo[n], vmax);
      const float al = exp2f((mo[n] - mn) * SCL);
      const float mnC = mn * SCL;
      mo[n] = mn;
      float ps = 0.f;
#pragma unroll
      for (int m = 0; m < 4; ++m) {
        float p0 = exp2f(__builtin_fmaf(sc[m][n][0], SCL, -mnC));
        float p1 = exp2f(__builtin_fmaf(sc[m][n][1], SCL, -mnC));
        float p2 = exp2f(__builtin_fmaf(sc[m][n][2], SCL, -mnC));
        float p3 = exp2f(__builtin_fmaf(sc[m][n][3], SCL, -mnC));
        ps += (p0 + p1) + (p2 + p3);
        uint2 pk;  // truncation pack via v_perm (P in [0,1], error <= 2^-8 rel)
        pk.x = __builtin_amdgcn_perm(__float_as_uint(p1), __float_as_uint(p0), 0x07060302);
        pk.y = __builtin_amdgcn_perm(__float_as_uint(p3), __float_as_uint(p2), 0x07060302);
        *reinterpret_cast<uint2*>(Ps + (qrow + n * 16 + lr) * 72 + m * 16 + q4) = pk;
      }
      ps += __shfl_xor(ps, 16, 64);
      ps += __shfl_xor(ps, 32, 64);
      lo[n] = lo[n] * al + ps;
#pragma unroll
      for (int md = 0; md < 4; ++md) {
        Oc[md][n][0] *= al; Oc[md][n][1] *= al;
        Oc[md][n][2] *= al; Oc[md][n][3] *= al;
      }
    }

    // O^T += V^T P^T (A = V frags from LDS, B = P rows from same-wave LDS region)
#pragma unroll
    for (int n = 0; n < 2; ++n) {
      bf16x8 bp0 = *reinterpret_cast<const bf16x8*>(Ps + (qrow + n * 16 + lr) * 72 + q8);
      bf16x8 bp1 = *reinterpret_cast<const bf16x8*>(Ps + (qrow + n * 16 + lr) * 72 + 32 + q8);
#pragma unroll
      for (int md = 0; md < 4; ++md) {
        Oc[md][n] = __builtin_amdgcn_mfma_f32_16x16x32_bf16(av0[md], bp0, Oc[md][n], 0, 0, 0);
        Oc[md][n] = __builtin_amdgcn_mfma_f32_16x16x32_bf16(av1[md], bp1, Oc[md][n], 0, 0, 0);
      }
    }
  }

  // partial epilogue: O'[q][d] = O^T/l (bf16), m/l raw fp32
  const size_t obase = (size_t)slot * 4096;
#pragma unroll
  for (int n = 0; n < 2; ++n) {
    const float inv = 1.f / lo[n];
    const int qlocal = qrow + n * 16 + lr;
#pragma unroll
    for (int md = 0; md < 4; ++md) {
      uint2 pk;
      pk.x = (uint32_t)f2bf(Oc[md][n][0] * inv) | ((uint32_t)f2bf(Oc[md][n][1] * inv) << 16);
      pk.y = (uint32_t)f2bf(Oc[md][n][2] * inv) | ((uint32_t)f2bf(Oc[md][n][3] * inv) << 16);
      *reinterpret_cast<uint2*>(Opart + obase + (size_t)qlocal * 64 + md * 16 + q4) = pk;
    }
    if (ln < 16) {
      Mpart[slot * 64 + qlocal] = mo[n];
      Lpart[slot * 64 + qlocal] = lo[n];
    }
  }
}

// merge partials: block per (bh, qi); thread t: q = t>>2, 16 d's at (t&3)*16
__global__ __launch_bounds__(256) void k_merge(
    const u16* __restrict__ Opart, const float* __restrict__ Mpart,
    const float* __restrict__ Lpart, u16* __restrict__ O) {
  const int bh = blockIdx.x >> 5, qi = blockIdx.x & 31;
  const int nc = (qi >> 3) + 1;
  const int band = qi >> 3;
  const int pre = (band == 0 ? 0 : band == 1 ? 8 : band == 2 ? 24 : 48) + (qi & 7) * (band + 1);
  const int slot0 = bh * 80 + pre;

  const int t = threadIdx.x;
  const int q = t >> 2, ds = (t & 3) * 16;

  float mc[4], lc[4];
  for (int cI = 0; cI < nc; ++cI) {
    mc[cI] = Mpart[(slot0 + cI) * 64 + q];
    lc[cI] = Lpart[(slot0 + cI) * 64 + q];
  }
  float M = mc[0];
  for (int cI = 1; cI < nc; ++cI) M = fmaxf(M, mc[cI]);
  float wc[4], wsum = 0.f;
  for (int cI = 0; cI < nc; ++cI) {
    wc[cI] = lc[cI] * exp2f((mc[cI] - M) * SCL);
    wsum += wc[cI];
  }
  const float inv = 1.f / wsum;

  float acc[16];
#pragma unroll
  for (int e = 0; e < 16; ++e) acc[e] = 0.f;
  for (int cI = 0; cI < nc; ++cI) {
    const u16* src = Opart + (size_t)(slot0 + cI) * 4096 + q * 64 + ds;
    uint4 a = *reinterpret_cast<const uint4*>(src);
    uint4 b = *reinterpret_cast<const uint4*>(src + 8);
    uint32_t uu[8] = {a.x, a.y, a.z, a.w, b.x, b.y, b.z, b.w};
    const float wci = wc[cI];
#pragma unroll
    for (int p = 0; p < 8; ++p) {
      acc[2 * p]     += wci * __uint_as_float(uu[p] << 16);
      acc[2 * p + 1] += wci * __uint_as_float(uu[p] & 0xFFFF0000u);
    }
  }

  const int bI = bh >> 4, hI = bh & 15;
  const size_t row = (size_t)(bI * 2048 + qi * 64 + q);
  u16* dst = O + row * 1024 + hI * 64 + ds;
  uint32_t op[8];
#pragma unroll
  for (int p = 0; p < 8; ++p)
    op[p] = (uint32_t)f2bf(acc[2 * p] * inv) | ((uint32_t)f2bf(acc[2 * p + 1] * inv) << 16);
  *reinterpret_cast<uint4*>(dst) = *reinterpret_cast<const uint4*>(&op[0]);
  *reinterpret_cast<uint4*>(dst + 8) = *reinterpret_cast<const uint4*>(&op[4]);
}

// ---------------- launch ----------------

extern "C" void kernel_launch(void* const* d_in, const int* in_sizes, int n_in,
                              void* d_out, int out_size, void* d_ws, size_t ws_size,
                              hipStream_t stream) {
  (void)in_sizes; (void)n_in; (void)out_size; (void)ws_size;
  const float* batch = (const float*)d_in[0];
  const int* ids     = (const int*)d_in[1];
  const float* W_Q   = (const float*)d_in[2];
  const float* W_K   = (const float*)d_in[3];
  const float* W_V   = (const float*)d_in[4];
  const float* b_Q   = (const float*)d_in[5];
  const float* b_K   = (const float*)d_in[6];
  const float* b_V   = (const float*)d_in[7];
  const float* W_O   = (const float*)d_in[8];
  const float* b_O   = (const float*)d_in[9];
  float* out = (float*)d_out;

  u16* ws = (u16*)d_ws;
  u16* Xbf   = ws;                        // 4,194,304
  u16* WqkvT = Xbf + 4194304;             // 3,145,728 (dead after k_qkv)
  u16* WoT   = WqkvT + 3145728;           // 1,048,576
  u16* Qb    = WoT + 1048576;             // 4,194,304
  u16* Kb    = Qb + 4194304;              // 4,194,304
  u16* Vtb   = Kb + 4194304;              // 4,194,304
  u16* Opart = Vtb + 4194304;             // 2560*4096 = 10,485,760
  float* Mpart = (float*)WqkvT;           // overlay dead WqkvT
  float* Lpart = Mpart + 163840;
  u16* Ob    = Xbf;                       // reuse X after k_qkv

  unsigned long long* padbits =
      (unsigned long long*)((char*)d_out + (size_t)out_size * 4 - 512);

  k_prologue<<<8208, 256, 0, stream>>>(batch, ids, W_Q, W_K, W_V, W_O, Xbf, WqkvT, WoT, padbits);
  k_qkv<<<dim3(32, 24), 256, 0, stream>>>(Xbf, WqkvT, b_Q, b_K, b_V, Qb, Kb, Vtb);
  k_attn<<<2560, 128, 0, stream>>>(Qb, Kb, Vtb, padbits, Opart, Mpart, Lpart);
  k_merge<<<1024, 256, 0, stream>>>(Opart, Mpart, Lpart, Ob);
  k_out<<<dim3(32, 8), 256, 0, stream>>>(Ob, WoT, b_O, out);
}

// Round 6
// 234.103 us; speedup vs baseline: 1.3160x; 1.0412x over previous
//
#include <hip/hip_runtime.h>
#include <stdint.h>

// B=2, S=2048, H=1024, NH=16, DK=DV=64, M=4096.
// prologue(fused cast/transpose/padbits) -> QKV gemm (Q pre-scaled by 0.125*log2e,
// V transposed) -> split-K flash attn (fixed-max softmax: p=exp2(s'), no online max)
// -> merge (l-weighted) -> out gemm.
// ws (u16 elems): X(4.19M) WqkvT(3.15M) WoT(1.05M) Q(4.19M) K(4.19M) Vt(4.19M) Opart(10.49M)
// Lpart overlays the dead WqkvT region after k_qkv. padbits in tail of d_out.

typedef unsigned short u16;
typedef __attribute__((ext_vector_type(8))) __bf16 bf16x8;
typedef __attribute__((ext_vector_type(4))) float f32x4;

#define SCL 0.18033688011112042f  // 0.125 * log2(e), folded into Q at projection

__device__ __forceinline__ u16 f2bf(float f) {
  union { float f; uint32_t u; } v; v.f = f;
  uint32_t r = v.u + 0x7FFFu + ((v.u >> 16) & 1u);  // RNE
  return (u16)(r >> 16);
}

__device__ __forceinline__ void gl_lds16(const u16* g, u16* l) {
  auto gp = reinterpret_cast<const __attribute__((address_space(1))) uint32_t*>(
      reinterpret_cast<uintptr_t>(g));
  auto lp = reinterpret_cast<__attribute__((address_space(3))) uint32_t*>(
      reinterpret_cast<uintptr_t>(l));
  __builtin_amdgcn_global_load_lds(gp, lp, 16, 0, 0);
}

// ---------------- fused prologue ----------------
__global__ void k_prologue(const float* __restrict__ batch, const int* __restrict__ ids,
                           const float* __restrict__ W_Q, const float* __restrict__ W_K,
                           const float* __restrict__ W_V, const float* __restrict__ W_O,
                           u16* __restrict__ Xbf, u16* __restrict__ dqkv, u16* __restrict__ dwo,
                           unsigned long long* __restrict__ pb) {
  __shared__ float tile[32][33];
  const int bx = blockIdx.x, t = threadIdx.x;
  if (bx < 4096) {
    int idx = (bx * 256 + t) * 4;
    const float4 v = *reinterpret_cast<const float4*>(batch + idx);
    uint2 o;
    o.x = (uint32_t)f2bf(v.x) | ((uint32_t)f2bf(v.y) << 16);
    o.y = (uint32_t)f2bf(v.z) | ((uint32_t)f2bf(v.w) << 16);
    *reinterpret_cast<uint2*>(Xbf + idx) = o;
  } else if (bx < 8192) {
    int b2 = bx - 4096;
    int z = b2 >> 10;
    b2 &= 1023;
    const float* src = z == 0 ? W_Q : (z == 1 ? W_K : (z == 2 ? W_V : W_O));
    u16* dst = z < 3 ? dqkv + (size_t)z * 1024 * 1024 : dwo;
    int c0 = (b2 & 31) * 32, r0 = (b2 >> 5) * 32;
    int tx = t & 31, ty = t >> 5;
#pragma unroll
    for (int i = 0; i < 4; ++i)
      tile[ty + i * 8][tx] = src[(size_t)(r0 + ty + i * 8) * 1024 + c0 + tx];
    __syncthreads();
#pragma unroll
    for (int i = 0; i < 4; ++i)
      dst[(size_t)(c0 + ty + i * 8) * 1024 + r0 + tx] = f2bf(tile[tx][ty + i * 8]);
  } else {
    int idx = (bx - 8192) * 4 + (t >> 6);
    int ln = t & 63;
    int b = idx >> 5, j = idx & 31;
    unsigned long long m = __ballot(ids[b * 2048 + j * 64 + ln] == 0);
    if (ln == 0) pb[idx] = m;
  }
}

// ---------------- GEMM core (m97 structure) ----------------

__device__ __forceinline__ void gemm_tile_acc(
    const u16* __restrict__ A, const u16* __restrict__ Bt, int K,
    int tm, int tn, u16* As, u16* Bs, f32x4 acc[4][4]) {
  const int t = threadIdx.x, wv = t >> 6, ln = t & 63;
  const int wr = (wv & 1) * 64, wc = (wv >> 1) * 64;
  const int lr = ln & 15, q8 = (ln >> 4) * 8;
  const int srow = ln >> 2, scol = (ln & 3) * 8;

  for (int k0 = 0; k0 < K; k0 += 32) {
#pragma unroll
    for (int i = 0; i < 2; ++i) {
      int c = wv + i * 4;
      gl_lds16(A + (size_t)(tm + c * 16 + srow) * K + k0 + scol, As + c * 512 + ln * 8);
      gl_lds16(Bt + (size_t)(tn + c * 16 + srow) * K + k0 + scol, Bs + c * 512 + ln * 8);
    }
    __syncthreads();
    bf16x8 av[4], bv[4];
#pragma unroll
    for (int m = 0; m < 4; ++m)
      av[m] = *reinterpret_cast<const bf16x8*>(As + (wr + m * 16 + lr) * 32 + q8);
#pragma unroll
    for (int n = 0; n < 4; ++n)
      bv[n] = *reinterpret_cast<const bf16x8*>(Bs + (wc + n * 16 + lr) * 32 + q8);
#pragma unroll
    for (int m = 0; m < 4; ++m)
#pragma unroll
      for (int n = 0; n < 4; ++n)
        acc[m][n] = __builtin_amdgcn_mfma_f32_16x16x32_bf16(av[m], bv[n], acc[m][n], 0, 0, 0);
    __syncthreads();
  }
}

// QKV projection. Q (pre-scaled by SCL), K -> [bh][s][64]; V -> TRANSPOSED [bh][64][2048]
__global__ __launch_bounds__(256) void k_qkv(
    const u16* __restrict__ X, const u16* __restrict__ Wt,
    const float* __restrict__ bQ, const float* __restrict__ bK, const float* __restrict__ bV,
    u16* __restrict__ Q, u16* __restrict__ Kd, u16* __restrict__ V) {
  __shared__ __align__(16) u16 As[128 * 32];
  __shared__ __align__(16) u16 Bs[128 * 32];
  f32x4 acc[4][4] = {};
  const int tm = blockIdx.x * 128, tn = blockIdx.y * 128;
  gemm_tile_acc(X, Wt, 1024, tm, tn, As, Bs, acc);

  const int t = threadIdx.x, wv = t >> 6, ln = t & 63;
  const int wr = (wv & 1) * 64, wc = (wv >> 1) * 64;
  const int lr = ln & 15, q4 = (ln >> 4) * 4;
  const int which = tn >> 10;

  if (which < 2) {
    u16* dst = which == 0 ? Q : Kd;
    const float* bias = which == 0 ? bQ : bK;
    const float scl = which == 0 ? SCL : 1.0f;
#pragma unroll
    for (int n = 0; n < 4; ++n) {
      int gc = tn + wc + n * 16 + lr;
      int f = gc & 1023;
      float bb = bias[f];
      int h = f >> 6, dd = f & 63;
#pragma unroll
      for (int m = 0; m < 4; ++m)
#pragma unroll
        for (int r = 0; r < 4; ++r) {
          int gr = tm + wr + m * 16 + q4 + r;
          int b = gr >> 11, s = gr & 2047;
          dst[((size_t)((b * 16 + h) * 2048 + s)) * 64 + dd] = f2bf((acc[m][n][r] + bb) * scl);
        }
    }
  } else {
#pragma unroll
    for (int n = 0; n < 4; ++n) {
      int gc = tn + wc + n * 16 + lr;
      int f = gc & 1023;
      float bb = bV[f];
      int h = f >> 6, dd = f & 63;
#pragma unroll
      for (int m = 0; m < 4; ++m) {
        int gr0 = tm + wr + m * 16 + q4;
        int b = gr0 >> 11, s0 = gr0 & 2047;
        uint2 pk;
        pk.x = (uint32_t)f2bf(acc[m][n][0] + bb) | ((uint32_t)f2bf(acc[m][n][1] + bb) << 16);
        pk.y = (uint32_t)f2bf(acc[m][n][2] + bb) | ((uint32_t)f2bf(acc[m][n][3] + bb) << 16);
        *reinterpret_cast<uint2*>(V + ((size_t)((b * 16 + h) * 64 + dd)) * 2048 + s0) = pk;
      }
    }
  }
}

// Output projection -> fp32 out
__global__ __launch_bounds__(256) void k_out(
    const u16* __restrict__ O, const u16* __restrict__ WoT,
    const float* __restrict__ bO, float* __restrict__ out) {
  __shared__ __align__(16) u16 As[128 * 32];
  __shared__ __align__(16) u16 Bs[128 * 32];
  f32x4 acc[4][4] = {};
  const int tm = blockIdx.x * 128, tn = blockIdx.y * 128;
  gemm_tile_acc(O, WoT, 1024, tm, tn, As, Bs, acc);

  const int t = threadIdx.x, wv = t >> 6, ln = t & 63;
  const int wr = (wv & 1) * 64, wc = (wv >> 1) * 64;
  const int lr = ln & 15, q4 = (ln >> 4) * 4;
#pragma unroll
  for (int n = 0; n < 4; ++n) {
    int gc = tn + wc + n * 16 + lr;
    float bb = bO[gc];
#pragma unroll
    for (int m = 0; m < 4; ++m)
#pragma unroll
      for (int r = 0; r < 4; ++r) {
        int gr = tm + wr + m * 16 + q4 + r;
        out[(size_t)gr * 1024 + gc] = acc[m][n][r] + bb;
      }
  }
}

// ---------------- split-K flash attention (fixed-max softmax) ----------------
// Same band decode as R4/R5. p = exp2(s') with s' = (q.k)*SCL already scaled via Q.
// No online max: no rescale, no per-tile shuffles; l reduced once at epilogue.
__global__ __launch_bounds__(128) void k_attn(
    const u16* __restrict__ Q, const u16* __restrict__ K, const u16* __restrict__ Vt,
    const unsigned long long* __restrict__ padbits,
    u16* __restrict__ Opart, float* __restrict__ Lpart) {
  __shared__ __align__(16) u16 Ks0[2048], Ks1[2048], Vs0[2048], Vs1[2048];
  __shared__ __align__(16) u16 Ps[64 * 72];

  const int id = blockIdx.x;
  const int bh = id & 31;
  const int w = 79 - (id >> 5);
  int qi, c;
  if (w < 8)       { qi = w;                   c = 0; }
  else if (w < 24) { qi = 8 + ((w - 8) >> 1);  c = (w - 8) & 1; }
  else if (w < 48) { qi = 16 + (w - 24) / 3;   c = (w - 24) % 3; }
  else             { qi = 24 + ((w - 48) >> 2); c = (w - 48) & 3; }
  const int jts = c * 8;
  const int jte = min(qi + 1, jts + 8);
  const int slot = bh * 80 + w;

  const int bI = bh >> 4;
  const int q0 = qi * 64;
  const u16* Qg = Q + (size_t)bh * 2048 * 64;
  const u16* Kg = K + (size_t)bh * 2048 * 64;
  const u16* Vg = Vt + (size_t)bh * 64 * 2048;

  const int t = threadIdx.x, wv = t >> 6, ln = t & 63;
  const int lr = ln & 15, q4 = (ln >> 4) * 4, q8 = (ln >> 4) * 8;
  const int qbase = q0 + wv * 32;
  const int qrow = wv * 32;
  const int srow = ln >> 2, scol = (ln & 3) * 8;

  bf16x8 bq[2][2];
#pragma unroll
  for (int n = 0; n < 2; ++n)
#pragma unroll
    for (int ks = 0; ks < 2; ++ks)
      bq[n][ks] = *reinterpret_cast<const bf16x8*>(
          Qg + (size_t)(qbase + n * 16 + lr) * 64 + ks * 32 + q8);

  float lo[2] = {0.f, 0.f};
  f32x4 Oc[4][2] = {};

  auto stage = [&](int kb) {
    if (wv == 0) {
#pragma unroll
      for (int cc = 0; cc < 4; ++cc) {
        gl_lds16(Kg + (size_t)(kb + cc * 16 + srow) * 64 + scol, Ks0 + cc * 512 + ln * 8);
        gl_lds16(Kg + (size_t)(kb + cc * 16 + srow) * 64 + 32 + scol, Ks1 + cc * 512 + ln * 8);
      }
    } else {
#pragma unroll
      for (int cc = 0; cc < 4; ++cc) {
        gl_lds16(Vg + (size_t)(cc * 16 + srow) * 2048 + kb + scol, Vs0 + cc * 512 + ln * 8);
        gl_lds16(Vg + (size_t)(cc * 16 + srow) * 2048 + kb + 32 + scol, Vs1 + cc * 512 + ln * 8);
      }
    }
  };
  stage(jts * 64);

  for (int j = jts; j < jte; ++j) {
    const int kb = j * 64;
    const unsigned long long pb = padbits[bI * 32 + j];
    const bool masked = (kb + 63 > qbase) || (pb != 0);
    __syncthreads();  // B1: staging of tile j complete

    // S'^T = K (Q*SCL)^T from LDS frags
    f32x4 sc[4][2] = {};
    {
      bf16x8 ak0[4], ak1[4];
#pragma unroll
      for (int m = 0; m < 4; ++m) {
        ak0[m] = *reinterpret_cast<const bf16x8*>(Ks0 + (m * 16 + lr) * 32 + q8);
        ak1[m] = *reinterpret_cast<const bf16x8*>(Ks1 + (m * 16 + lr) * 32 + q8);
      }
#pragma unroll
      for (int m = 0; m < 4; ++m)
#pragma unroll
        for (int n = 0; n < 2; ++n) {
          sc[m][n] = __builtin_amdgcn_mfma_f32_16x16x32_bf16(ak0[m], bq[n][0], sc[m][n], 0, 0, 0);
          sc[m][n] = __builtin_amdgcn_mfma_f32_16x16x32_bf16(ak1[m], bq[n][1], sc[m][n], 0, 0, 0);
        }
    }
    bf16x8 av0[4], av1[4];
#pragma unroll
    for (int md = 0; md < 4; ++md) {
      av0[md] = *reinterpret_cast<const bf16x8*>(Vs0 + (md * 16 + lr) * 32 + q8);
      av1[md] = *reinterpret_cast<const bf16x8*>(Vs1 + (md * 16 + lr) * 32 + q8);
    }
    __syncthreads();  // B2: all frag reads done
    if (j + 1 < jte) stage(kb + 64);  // async prefetch overlaps softmax+PV

    // fixed-max softmax: p = exp2(s'), lane-local l accumulation
#pragma unroll
    for (int n = 0; n < 2; ++n) {
      if (masked) {
        const int qabs = qbase + n * 16 + lr;
#pragma unroll
        for (int m = 0; m < 4; ++m)
#pragma unroll
          for (int r = 0; r < 4; ++r) {
            const int sl = m * 16 + q4 + r;
            const bool dead = (kb + sl > qabs) || ((pb >> sl) & 1ull);
            sc[m][n][r] = dead ? -1e30f : sc[m][n][r];
          }
      }
      float ps = 0.f;
#pragma unroll
      for (int m = 0; m < 4; ++m) {
        float p0 = exp2f(sc[m][n][0]);
        float p1 = exp2f(sc[m][n][1]);
        float p2 = exp2f(sc[m][n][2]);
        float p3 = exp2f(sc[m][n][3]);
        ps += (p0 + p1) + (p2 + p3);
        uint2 pk;  // truncation pack via v_perm
        pk.x = __builtin_amdgcn_perm(__float_as_uint(p1), __float_as_uint(p0), 0x07060302);
        pk.y = __builtin_amdgcn_perm(__float_as_uint(p3), __float_as_uint(p2), 0x07060302);
        *reinterpret_cast<uint2*>(Ps + (qrow + n * 16 + lr) * 72 + m * 16 + q4) = pk;
      }
      lo[n] += ps;
    }

    // O^T += V^T P^T
#pragma unroll
    for (int n = 0; n < 2; ++n) {
      bf16x8 bp0 = *reinterpret_cast<const bf16x8*>(Ps + (qrow + n * 16 + lr) * 72 + q8);
      bf16x8 bp1 = *reinterpret_cast<const bf16x8*>(Ps + (qrow + n * 16 + lr) * 72 + 32 + q8);
#pragma unroll
      for (int md = 0; md < 4; ++md) {
        Oc[md][n] = __builtin_amdgcn_mfma_f32_16x16x32_bf16(av0[md], bp0, Oc[md][n], 0, 0, 0);
        Oc[md][n] = __builtin_amdgcn_mfma_f32_16x16x32_bf16(av1[md], bp1, Oc[md][n], 0, 0, 0);
      }
    }
  }

  // epilogue: single cross-lane l reduction; O'[q][d] = O^T/l (bf16), l raw fp32
  const size_t obase = (size_t)slot * 4096;
#pragma unroll
  for (int n = 0; n < 2; ++n) {
    lo[n] += __shfl_xor(lo[n], 16, 64);
    lo[n] += __shfl_xor(lo[n], 32, 64);
    const float inv = 1.f / lo[n];
    const int qlocal = qrow + n * 16 + lr;
#pragma unroll
    for (int md = 0; md < 4; ++md) {
      uint2 pk;
      pk.x = (uint32_t)f2bf(Oc[md][n][0] * inv) | ((uint32_t)f2bf(Oc[md][n][1] * inv) << 16);
      pk.y = (uint32_t)f2bf(Oc[md][n][2] * inv) | ((uint32_t)f2bf(Oc[md][n][3] * inv) << 16);
      *reinterpret_cast<uint2*>(Opart + obase + (size_t)qlocal * 64 + md * 16 + q4) = pk;
    }
    if (ln < 16) Lpart[slot * 64 + qlocal] = lo[n];
  }
}

// merge partials: l-weighted average. block per (bh, qi); thread t: q=t>>2, 16 d at (t&3)*16
__global__ __launch_bounds__(256) void k_merge(
    const u16* __restrict__ Opart, const float* __restrict__ Lpart, u16* __restrict__ O) {
  const int bh = blockIdx.x >> 5, qi = blockIdx.x & 31;
  const int nc = (qi >> 3) + 1;
  const int band = qi >> 3;
  const int pre = (band == 0 ? 0 : band == 1 ? 8 : band == 2 ? 24 : 48) + (qi & 7) * (band + 1);
  const int slot0 = bh * 80 + pre;

  const int t = threadIdx.x;
  const int q = t >> 2, ds = (t & 3) * 16;

  float wc[4], wsum = 0.f;
  for (int cI = 0; cI < nc; ++cI) {
    wc[cI] = Lpart[(slot0 + cI) * 64 + q];
    wsum += wc[cI];
  }
  const float inv = 1.f / wsum;

  float acc[16];
#pragma unroll
  for (int e = 0; e < 16; ++e) acc[e] = 0.f;
  for (int cI = 0; cI < nc; ++cI) {
    const u16* src = Opart + (size_t)(slot0 + cI) * 4096 + q * 64 + ds;
    uint4 a = *reinterpret_cast<const uint4*>(src);
    uint4 b = *reinterpret_cast<const uint4*>(src + 8);
    uint32_t uu[8] = {a.x, a.y, a.z, a.w, b.x, b.y, b.z, b.w};
    const float wci = wc[cI];
#pragma unroll
    for (int p = 0; p < 8; ++p) {
      acc[2 * p]     += wci * __uint_as_float(uu[p] << 16);
      acc[2 * p + 1] += wci * __uint_as_float(uu[p] & 0xFFFF0000u);
    }
  }

  const int bI = bh >> 4, hI = bh & 15;
  const size_t row = (size_t)(bI * 2048 + qi * 64 + q);
  u16* dst = O + row * 1024 + hI * 64 + ds;
  uint32_t op[8];
#pragma unroll
  for (int p = 0; p < 8; ++p)
    op[p] = (uint32_t)f2bf(acc[2 * p] * inv) | ((uint32_t)f2bf(acc[2 * p + 1] * inv) << 16);
  *reinterpret_cast<uint4*>(dst) = *reinterpret_cast<const uint4*>(&op[0]);
  *reinterpret_cast<uint4*>(dst + 8) = *reinterpret_cast<const uint4*>(&op[4]);
}

// ---------------- launch ----------------

extern "C" void kernel_launch(void* const* d_in, const int* in_sizes, int n_in,
                              void* d_out, int out_size, void* d_ws, size_t ws_size,
                              hipStream_t stream) {
  (void)in_sizes; (void)n_in; (void)out_size; (void)ws_size;
  const float* batch = (const float*)d_in[0];
  const int* ids     = (const int*)d_in[1];
  const float* W_Q   = (const float*)d_in[2];
  const float* W_K   = (const float*)d_in[3];
  const float* W_V   = (const float*)d_in[4];
  const float* b_Q   = (const float*)d_in[5];
  const float* b_K   = (const float*)d_in[6];
  const float* b_V   = (const float*)d_in[7];
  const float* W_O   = (const float*)d_in[8];
  const float* b_O   = (const float*)d_in[9];
  float* out = (float*)d_out;

  u16* ws = (u16*)d_ws;
  u16* Xbf   = ws;                        // 4,194,304
  u16* WqkvT = Xbf + 4194304;             // 3,145,728 (dead after k_qkv)
  u16* WoT   = WqkvT + 3145728;           // 1,048,576
  u16* Qb    = WoT + 1048576;             // 4,194,304
  u16* Kb    = Qb + 4194304;              // 4,194,304
  u16* Vtb   = Kb + 4194304;              // 4,194,304
  u16* Opart = Vtb + 4194304;             // 2560*4096 = 10,485,760
  float* Lpart = (float*)WqkvT;           // overlay dead WqkvT (163,840 f32)
  u16* Ob    = Xbf;                       // reuse X after k_qkv

  unsigned long long* padbits =
      (unsigned long long*)((char*)d_out + (size_t)out_size * 4 - 512);

  k_prologue<<<8208, 256, 0, stream>>>(batch, ids, W_Q, W_K, W_V, W_O, Xbf, WqkvT, WoT, padbits);
  k_qkv<<<dim3(32, 24), 256, 0, stream>>>(Xbf, WqkvT, b_Q, b_K, b_V, Qb, Kb, Vtb);
  k_attn<<<2560, 128, 0, stream>>>(Qb, Kb, Vtb, padbits, Opart, Lpart);
  k_merge<<<1024, 256, 0, stream>>>(Opart, Lpart, Ob);
  k_out<<<dim3(32, 8), 256, 0, stream>>>(Ob, WoT, b_O, out);
}

// Round 7
// 223.557 us; speedup vs baseline: 1.3780x; 1.0472x over previous
//
#include <hip/hip_runtime.h>
#include <stdint.h>

// B=2, S=2048, H=1024, NH=16, DK=DV=64, M=4096.
// prologue(cast/transpose/padbits) -> QKV gemm with MFMA-fragment-ready epilogue layouts
// (Q pre-scaled by 0.125*log2e) -> BARRIER-FREE split-K flash attn (coalesced frag loads
// straight from global, P via wave-private LDS) -> merge (l-weighted) -> out gemm.
// Tiled layouts (u16):
//   Qt[((bh*64+qt)*4 + n*2 + kh)*512 + ln*8 + e]   qt=q>>5, n=(q&31)>>4, frag B-operand
//   Kt[((bh*32+j)*8 + kh*4 + m)*512 + ln*8 + e]    j=k>>6,  m=(k&63)>>4, frag A-operand
//   Vt[((bh*32+j)*8 + kh*4 + md)*512 + ln*8 + e]   V^T frag A-operand (row=d, col=k)
// ws (u16): X(4.19M) WqkvT(3.15M) WoT(1.05M) Qt,Kt,Vt(4.19M ea) Opart(10.49M); Lpart
// overlays dead WqkvT. padbits in tail of d_out.

typedef unsigned short u16;
typedef __attribute__((ext_vector_type(8))) __bf16 bf16x8;
typedef __attribute__((ext_vector_type(4))) float f32x4;

#define SCL 0.18033688011112042f  // 0.125 * log2(e), folded into Q at projection

__device__ __forceinline__ u16 f2bf(float f) {
  union { float f; uint32_t u; } v; v.f = f;
  uint32_t r = v.u + 0x7FFFu + ((v.u >> 16) & 1u);  // RNE
  return (u16)(r >> 16);
}

__device__ __forceinline__ void gl_lds16(const u16* g, u16* l) {
  auto gp = reinterpret_cast<const __attribute__((address_space(1))) uint32_t*>(
      reinterpret_cast<uintptr_t>(g));
  auto lp = reinterpret_cast<__attribute__((address_space(3))) uint32_t*>(
      reinterpret_cast<uintptr_t>(l));
  __builtin_amdgcn_global_load_lds(gp, lp, 16, 0, 0);
}

// ---------------- fused prologue ----------------
__global__ void k_prologue(const float* __restrict__ batch, const int* __restrict__ ids,
                           const float* __restrict__ W_Q, const float* __restrict__ W_K,
                           const float* __restrict__ W_V, const float* __restrict__ W_O,
                           u16* __restrict__ Xbf, u16* __restrict__ dqkv, u16* __restrict__ dwo,
                           unsigned long long* __restrict__ pb) {
  __shared__ float tile[32][33];
  const int bx = blockIdx.x, t = threadIdx.x;
  if (bx < 4096) {
    int idx = (bx * 256 + t) * 4;
    const float4 v = *reinterpret_cast<const float4*>(batch + idx);
    uint2 o;
    o.x = (uint32_t)f2bf(v.x) | ((uint32_t)f2bf(v.y) << 16);
    o.y = (uint32_t)f2bf(v.z) | ((uint32_t)f2bf(v.w) << 16);
    *reinterpret_cast<uint2*>(Xbf + idx) = o;
  } else if (bx < 8192) {
    int b2 = bx - 4096;
    int z = b2 >> 10;
    b2 &= 1023;
    const float* src = z == 0 ? W_Q : (z == 1 ? W_K : (z == 2 ? W_V : W_O));
    u16* dst = z < 3 ? dqkv + (size_t)z * 1024 * 1024 : dwo;
    int c0 = (b2 & 31) * 32, r0 = (b2 >> 5) * 32;
    int tx = t & 31, ty = t >> 5;
#pragma unroll
    for (int i = 0; i < 4; ++i)
      tile[ty + i * 8][tx] = src[(size_t)(r0 + ty + i * 8) * 1024 + c0 + tx];
    __syncthreads();
#pragma unroll
    for (int i = 0; i < 4; ++i)
      dst[(size_t)(c0 + ty + i * 8) * 1024 + r0 + tx] = f2bf(tile[tx][ty + i * 8]);
  } else {
    int idx = (bx - 8192) * 4 + (t >> 6);
    int ln = t & 63;
    int b = idx >> 5, j = idx & 31;
    unsigned long long m = __ballot(ids[b * 2048 + j * 64 + ln] == 0);
    if (ln == 0) pb[idx] = m;
  }
}

// ---------------- GEMM core (m97 structure) ----------------

__device__ __forceinline__ void gemm_tile_acc(
    const u16* __restrict__ A, const u16* __restrict__ Bt, int K,
    int tm, int tn, u16* As, u16* Bs, f32x4 acc[4][4]) {
  const int t = threadIdx.x, wv = t >> 6, ln = t & 63;
  const int wr = (wv & 1) * 64, wc = (wv >> 1) * 64;
  const int lr = ln & 15, q8 = (ln >> 4) * 8;
  const int srow = ln >> 2, scol = (ln & 3) * 8;

  for (int k0 = 0; k0 < K; k0 += 32) {
#pragma unroll
    for (int i = 0; i < 2; ++i) {
      int c = wv + i * 4;
      gl_lds16(A + (size_t)(tm + c * 16 + srow) * K + k0 + scol, As + c * 512 + ln * 8);
      gl_lds16(Bt + (size_t)(tn + c * 16 + srow) * K + k0 + scol, Bs + c * 512 + ln * 8);
    }
    __syncthreads();
    bf16x8 av[4], bv[4];
#pragma unroll
    for (int m = 0; m < 4; ++m)
      av[m] = *reinterpret_cast<const bf16x8*>(As + (wr + m * 16 + lr) * 32 + q8);
#pragma unroll
    for (int n = 0; n < 4; ++n)
      bv[n] = *reinterpret_cast<const bf16x8*>(Bs + (wc + n * 16 + lr) * 32 + q8);
#pragma unroll
    for (int m = 0; m < 4; ++m)
#pragma unroll
      for (int n = 0; n < 4; ++n)
        acc[m][n] = __builtin_amdgcn_mfma_f32_16x16x32_bf16(av[m], bv[n], acc[m][n], 0, 0, 0);
    __syncthreads();
  }
}

// QKV projection into fragment-ready tiled layouts (see header comment).
__global__ __launch_bounds__(256) void k_qkv(
    const u16* __restrict__ X, const u16* __restrict__ Wt,
    const float* __restrict__ bQ, const float* __restrict__ bK, const float* __restrict__ bV,
    u16* __restrict__ Qt, u16* __restrict__ Kt, u16* __restrict__ Vt) {
  __shared__ __align__(16) u16 As[128 * 32];
  __shared__ __align__(16) u16 Bs[128 * 32];
  f32x4 acc[4][4] = {};
  const int tm = blockIdx.x * 128, tn = blockIdx.y * 128;
  gemm_tile_acc(X, Wt, 1024, tm, tn, As, Bs, acc);

  const int t = threadIdx.x, wv = t >> 6, ln = t & 63;
  const int wr = (wv & 1) * 64, wc = (wv >> 1) * 64;
  const int lr = ln & 15, q4 = (ln >> 4) * 4;
  const int which = tn >> 10;

  if (which == 0) {  // Q, pre-scaled by SCL
#pragma unroll
    for (int n = 0; n < 4; ++n) {
      int f = (tn + wc + n * 16 + lr) & 1023;
      float bb = bQ[f];
      int h = f >> 6, dd = f & 63;
      int kh = dd >> 5, qq = (dd & 31) >> 3, e = dd & 7;
#pragma unroll
      for (int m = 0; m < 4; ++m)
#pragma unroll
        for (int r = 0; r < 4; ++r) {
          int gr = tm + wr + m * 16 + q4 + r;
          int b = gr >> 11, s = gr & 2047;
          int bh = b * 16 + h;
          size_t addr = (((size_t)(bh * 64 + (s >> 5)) * 4 + ((s & 31) >> 4) * 2 + kh) << 9) +
                        ((s & 15) + 16 * qq) * 8 + e;
          Qt[addr] = f2bf((acc[m][n][r] + bb) * SCL);
        }
    }
  } else if (which == 1) {  // K
#pragma unroll
    for (int n = 0; n < 4; ++n) {
      int f = (tn + wc + n * 16 + lr) & 1023;
      float bb = bK[f];
      int h = f >> 6, dd = f & 63;
      int kh = dd >> 5, qq = (dd & 31) >> 3, e = dd & 7;
#pragma unroll
      for (int m = 0; m < 4; ++m)
#pragma unroll
        for (int r = 0; r < 4; ++r) {
          int gr = tm + wr + m * 16 + q4 + r;
          int b = gr >> 11, s = gr & 2047;
          int bh = b * 16 + h;
          size_t addr = (((size_t)(bh * 32 + (s >> 6)) * 8 + kh * 4 + ((s & 63) >> 4)) << 9) +
                        ((s & 15) + 16 * qq) * 8 + e;
          Kt[addr] = f2bf(acc[m][n][r] + bb);
        }
    }
  } else {  // V -> V^T fragment tiles, 4 contiguous k-elems per packed store
#pragma unroll
    for (int n = 0; n < 4; ++n) {
      int f = (tn + wc + n * 16 + lr) & 1023;
      float bb = bV[f];
      int h = f >> 6, dd = f & 63;
      int md = dd >> 4, lrv = dd & 15;
#pragma unroll
      for (int m = 0; m < 4; ++m) {
        int gr0 = tm + wr + m * 16 + q4;
        int b = gr0 >> 11, s0 = gr0 & 2047;
        int bh = b * 16 + h;
        int j = s0 >> 6, kh = (s0 & 63) >> 5, qv = (s0 & 31) >> 3, e0 = s0 & 7;
        size_t addr = (((size_t)(bh * 32 + j) * 8 + kh * 4 + md) << 9) +
                      (lrv + 16 * qv) * 8 + e0;
        uint2 pk;
        pk.x = (uint32_t)f2bf(acc[m][n][0] + bb) | ((uint32_t)f2bf(acc[m][n][1] + bb) << 16);
        pk.y = (uint32_t)f2bf(acc[m][n][2] + bb) | ((uint32_t)f2bf(acc[m][n][3] + bb) << 16);
        *reinterpret_cast<uint2*>(Vt + addr) = pk;
      }
    }
  }
}

// Output projection -> fp32 out
__global__ __launch_bounds__(256) void k_out(
    const u16* __restrict__ O, const u16* __restrict__ WoT,
    const float* __restrict__ bO, float* __restrict__ out) {
  __shared__ __align__(16) u16 As[128 * 32];
  __shared__ __align__(16) u16 Bs[128 * 32];
  f32x4 acc[4][4] = {};
  const int tm = blockIdx.x * 128, tn = blockIdx.y * 128;
  gemm_tile_acc(O, WoT, 1024, tm, tn, As, Bs, acc);

  const int t = threadIdx.x, wv = t >> 6, ln = t & 63;
  const int wr = (wv & 1) * 64, wc = (wv >> 1) * 64;
  const int lr = ln & 15, q4 = (ln >> 4) * 4;
#pragma unroll
  for (int n = 0; n < 4; ++n) {
    int gc = tn + wc + n * 16 + lr;
    float bb = bO[gc];
#pragma unroll
    for (int m = 0; m < 4; ++m)
#pragma unroll
      for (int r = 0; r < 4; ++r) {
        int gr = tm + wr + m * 16 + q4 + r;
        out[(size_t)gr * 1024 + gc] = acc[m][n][r] + bb;
      }
  }
}

// ---------------- barrier-free split-K flash attention ----------------
// Same 2560-item band decode. Frags load coalesced from tiled Qt/Kt/Vt; K frags
// register-rotated one tile ahead; V frags issued early (consumed at PV). P goes
// through wave-private LDS rows. NO __syncthreads anywhere.
__global__ __launch_bounds__(128) void k_attn(
    const u16* __restrict__ Qt, const u16* __restrict__ Kt, const u16* __restrict__ Vt,
    const unsigned long long* __restrict__ padbits,
    u16* __restrict__ Opart, float* __restrict__ Lpart) {
  __shared__ __align__(16) u16 Ps[64 * 72];

  const int id = blockIdx.x;
  const int bh = id & 31;
  const int w = 79 - (id >> 5);
  int qi, c;
  if (w < 8)       { qi = w;                   c = 0; }
  else if (w < 24) { qi = 8 + ((w - 8) >> 1);  c = (w - 8) & 1; }
  else if (w < 48) { qi = 16 + (w - 24) / 3;   c = (w - 24) % 3; }
  else             { qi = 24 + ((w - 48) >> 2); c = (w - 48) & 3; }
  const int jts = c * 8;
  const int jte = min(qi + 1, jts + 8);
  const int slot = bh * 80 + w;

  const int bI = bh >> 4;
  const int t = threadIdx.x, wv = t >> 6, ln = t & 63;
  const int lr = ln & 15, q4 = (ln >> 4) * 4;
  const int qbase = qi * 64 + wv * 32;
  const int qrow = wv * 32;

  // Q B-frags: coalesced from Qt
  bf16x8 bq[2][2];
  {
    const u16* qb = Qt + (((size_t)(bh * 64 + (qbase >> 5)) * 4) << 9) + ln * 8;
#pragma unroll
    for (int n = 0; n < 2; ++n)
#pragma unroll
      for (int kh = 0; kh < 2; ++kh)
        bq[n][kh] = *reinterpret_cast<const bf16x8*>(qb + ((n * 2 + kh) << 9));
  }

  float lo[2] = {0.f, 0.f};
  f32x4 Oc[4][2] = {};

  const u16* Kb = Kt + (((size_t)bh * 32) << 12) + ln * 8;  // + j*8*512 + (kh*4+m)*512
  const u16* Vb = Vt + (((size_t)bh * 32) << 12) + ln * 8;

  // preload K frags for first tile
  bf16x8 ak0[4], ak1[4];
#pragma unroll
  for (int m = 0; m < 4; ++m) {
    ak0[m] = *reinterpret_cast<const bf16x8*>(Kb + ((size_t)jts << 12) + (m << 9));
    ak1[m] = *reinterpret_cast<const bf16x8*>(Kb + ((size_t)jts << 12) + ((4 + m) << 9));
  }

  for (int j = jts; j < jte; ++j) {
    const int kb = j * 64;
    const unsigned long long pb = padbits[bI * 32 + j];
    const bool masked = (kb + 63 > qbase) || (pb != 0);

    // V frags for this tile (consumed at PV — latency hidden by S+softmax)
    bf16x8 av0[4], av1[4];
#pragma unroll
    for (int md = 0; md < 4; ++md) {
      av0[md] = *reinterpret_cast<const bf16x8*>(Vb + ((size_t)j << 12) + (md << 9));
      av1[md] = *reinterpret_cast<const bf16x8*>(Vb + ((size_t)j << 12) + ((4 + md) << 9));
    }
    // next tile's K frags (register rotation)
    bf16x8 nk0[4], nk1[4];
    if (j + 1 < jte) {
#pragma unroll
      for (int m = 0; m < 4; ++m) {
        nk0[m] = *reinterpret_cast<const bf16x8*>(Kb + ((size_t)(j + 1) << 12) + (m << 9));
        nk1[m] = *reinterpret_cast<const bf16x8*>(Kb + ((size_t)(j + 1) << 12) + ((4 + m) << 9));
      }
    }

    // S'^T = K (Q*SCL)^T
    f32x4 sc[4][2] = {};
#pragma unroll
    for (int m = 0; m < 4; ++m)
#pragma unroll
      for (int n = 0; n < 2; ++n) {
        sc[m][n] = __builtin_amdgcn_mfma_f32_16x16x32_bf16(ak0[m], bq[n][0], sc[m][n], 0, 0, 0);
        sc[m][n] = __builtin_amdgcn_mfma_f32_16x16x32_bf16(ak1[m], bq[n][1], sc[m][n], 0, 0, 0);
      }

    // fixed-max softmax: p = exp2(s'), lane-local l
#pragma unroll
    for (int n = 0; n < 2; ++n) {
      if (masked) {
        const int qabs = qbase + n * 16 + lr;
#pragma unroll
        for (int m = 0; m < 4; ++m)
#pragma unroll
          for (int r = 0; r < 4; ++r) {
            const int sl = m * 16 + q4 + r;
            const bool dead = (kb + sl > qabs) || ((pb >> sl) & 1ull);
            sc[m][n][r] = dead ? -1e30f : sc[m][n][r];
          }
      }
      float ps = 0.f;
#pragma unroll
      for (int m = 0; m < 4; ++m) {
        float p0 = exp2f(sc[m][n][0]);
        float p1 = exp2f(sc[m][n][1]);
        float p2 = exp2f(sc[m][n][2]);
        float p3 = exp2f(sc[m][n][3]);
        ps += (p0 + p1) + (p2 + p3);
        uint2 pk;  // truncation pack via v_perm
        pk.x = __builtin_amdgcn_perm(__float_as_uint(p1), __float_as_uint(p0), 0x07060302);
        pk.y = __builtin_amdgcn_perm(__float_as_uint(p3), __float_as_uint(p2), 0x07060302);
        *reinterpret_cast<uint2*>(Ps + (qrow + n * 16 + lr) * 72 + m * 16 + q4) = pk;
      }
      lo[n] += ps;
    }

    // O^T += V^T P^T (P from same-wave LDS rows; lgkmcnt ordering only)
#pragma unroll
    for (int n = 0; n < 2; ++n) {
      const int q8n = (ln >> 4) * 8;
      bf16x8 bp0 = *reinterpret_cast<const bf16x8*>(Ps + (qrow + n * 16 + lr) * 72 + q8n);
      bf16x8 bp1 = *reinterpret_cast<const bf16x8*>(Ps + (qrow + n * 16 + lr) * 72 + 32 + q8n);
#pragma unroll
      for (int md = 0; md < 4; ++md) {
        Oc[md][n] = __builtin_amdgcn_mfma_f32_16x16x32_bf16(av0[md], bp0, Oc[md][n], 0, 0, 0);
        Oc[md][n] = __builtin_amdgcn_mfma_f32_16x16x32_bf16(av1[md], bp1, Oc[md][n], 0, 0, 0);
      }
    }

#pragma unroll
    for (int m = 0; m < 4; ++m) { ak0[m] = nk0[m]; ak1[m] = nk1[m]; }
  }

  // epilogue: single cross-lane l reduction; O'[q][d] = O^T/l (bf16), l raw fp32
  const size_t obase = (size_t)slot * 4096;
#pragma unroll
  for (int n = 0; n < 2; ++n) {
    lo[n] += __shfl_xor(lo[n], 16, 64);
    lo[n] += __shfl_xor(lo[n], 32, 64);
    const float inv = 1.f / lo[n];
    const int qlocal = qrow + n * 16 + lr;
#pragma unroll
    for (int md = 0; md < 4; ++md) {
      uint2 pk;
      pk.x = (uint32_t)f2bf(Oc[md][n][0] * inv) | ((uint32_t)f2bf(Oc[md][n][1] * inv) << 16);
      pk.y = (uint32_t)f2bf(Oc[md][n][2] * inv) | ((uint32_t)f2bf(Oc[md][n][3] * inv) << 16);
      *reinterpret_cast<uint2*>(Opart + obase + (size_t)qlocal * 64 + md * 16 + q4) = pk;
    }
    if (ln < 16) Lpart[slot * 64 + qlocal] = lo[n];
  }
}

// merge partials: l-weighted average. block per (bh, qi); thread t: q=t>>2, 16 d at (t&3)*16
__global__ __launch_bounds__(256) void k_merge(
    const u16* __restrict__ Opart, const float* __restrict__ Lpart, u16* __restrict__ O) {
  const int bh = blockIdx.x >> 5, qi = blockIdx.x & 31;
  const int nc = (qi >> 3) + 1;
  const int band = qi >> 3;
  const int pre = (band == 0 ? 0 : band == 1 ? 8 : band == 2 ? 24 : 48) + (qi & 7) * (band + 1);
  const int slot0 = bh * 80 + pre;

  const int t = threadIdx.x;
  const int q = t >> 2, ds = (t & 3) * 16;

  float wc[4], wsum = 0.f;
  for (int cI = 0; cI < nc; ++cI) {
    wc[cI] = Lpart[(slot0 + cI) * 64 + q];
    wsum += wc[cI];
  }
  const float inv = 1.f / wsum;

  float acc[16];
#pragma unroll
  for (int e = 0; e < 16; ++e) acc[e] = 0.f;
  for (int cI = 0; cI < nc; ++cI) {
    const u16* src = Opart + (size_t)(slot0 + cI) * 4096 + q * 64 + ds;
    uint4 a = *reinterpret_cast<const uint4*>(src);
    uint4 b = *reinterpret_cast<const uint4*>(src + 8);
    uint32_t uu[8] = {a.x, a.y, a.z, a.w, b.x, b.y, b.z, b.w};
    const float wci = wc[cI];
#pragma unroll
    for (int p = 0; p < 8; ++p) {
      acc[2 * p]     += wci * __uint_as_float(uu[p] << 16);
      acc[2 * p + 1] += wci * __uint_as_float(uu[p] & 0xFFFF0000u);
    }
  }

  const int bI = bh >> 4, hI = bh & 15;
  const size_t row = (size_t)(bI * 2048 + qi * 64 + q);
  u16* dst = O + row * 1024 + hI * 64 + ds;
  uint32_t op[8];
#pragma unroll
  for (int p = 0; p < 8; ++p)
    op[p] = (uint32_t)f2bf(acc[2 * p] * inv) | ((uint32_t)f2bf(acc[2 * p + 1] * inv) << 16);
  *reinterpret_cast<uint4*>(dst) = *reinterpret_cast<const uint4*>(&op[0]);
  *reinterpret_cast<uint4*>(dst + 8) = *reinterpret_cast<const uint4*>(&op[4]);
}

// ---------------- launch ----------------

extern "C" void kernel_launch(void* const* d_in, const int* in_sizes, int n_in,
                              void* d_out, int out_size, void* d_ws, size_t ws_size,
                              hipStream_t stream) {
  (void)in_sizes; (void)n_in; (void)out_size; (void)ws_size;
  const float* batch = (const float*)d_in[0];
  const int* ids     = (const int*)d_in[1];
  const float* W_Q   = (const float*)d_in[2];
  const float* W_K   = (const float*)d_in[3];
  const float* W_V   = (const float*)d_in[4];
  const float* b_Q   = (const float*)d_in[5];
  const float* b_K   = (const float*)d_in[6];
  const float* b_V   = (const float*)d_in[7];
  const float* W_O   = (const float*)d_in[8];
  const float* b_O   = (const float*)d_in[9];
  float* out = (float*)d_out;

  u16* ws = (u16*)d_ws;
  u16* Xbf   = ws;                        // 4,194,304
  u16* WqkvT = Xbf + 4194304;             // 3,145,728 (dead after k_qkv)
  u16* WoT   = WqkvT + 3145728;           // 1,048,576
  u16* Qtb   = WoT + 1048576;             // 4,194,304 (tiled)
  u16* Ktb   = Qtb + 4194304;             // 4,194,304 (tiled)
  u16* Vtb   = Ktb + 4194304;             // 4,194,304 (tiled V^T)
  u16* Opart = Vtb + 4194304;             // 2560*4096 = 10,485,760
  float* Lpart = (float*)WqkvT;           // overlay dead WqkvT (163,840 f32)
  u16* Ob    = Xbf;                       // reuse X after k_qkv

  unsigned long long* padbits =
      (unsigned long long*)((char*)d_out + (size_t)out_size * 4 - 512);

  k_prologue<<<8208, 256, 0, stream>>>(batch, ids, W_Q, W_K, W_V, W_O, Xbf, WqkvT, WoT, padbits);
  k_qkv<<<dim3(32, 24), 256, 0, stream>>>(Xbf, WqkvT, b_Q, b_K, b_V, Qtb, Ktb, Vtb);
  k_attn<<<2560, 128, 0, stream>>>(Qtb, Ktb, Vtb, padbits, Opart, Lpart);
  k_merge<<<1024, 256, 0, stream>>>(Opart, Lpart, Ob);
  k_out<<<dim3(32, 8), 256, 0, stream>>>(Ob, WoT, b_O, out);
}

// Round 8
// 221.455 us; speedup vs baseline: 1.3911x; 1.0095x over previous
//
#include <hip/hip_runtime.h>
#include <stdint.h>

// B=2, S=2048, H=1024, NH=16, DK=DV=64, M=4096.
// prologue(cast/transpose/padbits) -> QKV gemm with MFMA-fragment-ready epilogue layouts
// (Q pre-scaled by 0.125*log2e) -> BARRIER-FREE SOFTWARE-PIPELINED split-K flash attn
// (PV for tile j-1 overlaps the LDS round-trip of tile j) -> merge -> out gemm.
// Tiled layouts (u16):
//   Qt[((bh*64+qt)*4 + n*2 + kh)*512 + ln*8 + e]   qt=q>>5, n=(q&31)>>4, frag B-operand
//   Kt[((bh*32+j)*8 + kh*4 + m)*512 + ln*8 + e]    j=k>>6,  m=(k&63)>>4, frag A-operand
//   Vt[((bh*32+j)*8 + kh*4 + md)*512 + ln*8 + e]   V^T frag A-operand (row=d, col=k)
// ws (u16): X(4.19M) WqkvT(3.15M) WoT(1.05M) Qt,Kt,Vt(4.19M ea) Opart(10.49M); Lpart
// overlays dead WqkvT. padbits in tail of d_out.

typedef unsigned short u16;
typedef __attribute__((ext_vector_type(8))) __bf16 bf16x8;
typedef __attribute__((ext_vector_type(4))) float f32x4;

#define SCL 0.18033688011112042f  // 0.125 * log2(e), folded into Q at projection

__device__ __forceinline__ u16 f2bf(float f) {
  union { float f; uint32_t u; } v; v.f = f;
  uint32_t r = v.u + 0x7FFFu + ((v.u >> 16) & 1u);  // RNE
  return (u16)(r >> 16);
}

__device__ __forceinline__ void gl_lds16(const u16* g, u16* l) {
  auto gp = reinterpret_cast<const __attribute__((address_space(1))) uint32_t*>(
      reinterpret_cast<uintptr_t>(g));
  auto lp = reinterpret_cast<__attribute__((address_space(3))) uint32_t*>(
      reinterpret_cast<uintptr_t>(l));
  __builtin_amdgcn_global_load_lds(gp, lp, 16, 0, 0);
}

// ---------------- fused prologue ----------------
__global__ void k_prologue(const float* __restrict__ batch, const int* __restrict__ ids,
                           const float* __restrict__ W_Q, const float* __restrict__ W_K,
                           const float* __restrict__ W_V, const float* __restrict__ W_O,
                           u16* __restrict__ Xbf, u16* __restrict__ dqkv, u16* __restrict__ dwo,
                           unsigned long long* __restrict__ pb) {
  __shared__ float tile[32][33];
  const int bx = blockIdx.x, t = threadIdx.x;
  if (bx < 4096) {
    int idx = (bx * 256 + t) * 4;
    const float4 v = *reinterpret_cast<const float4*>(batch + idx);
    uint2 o;
    o.x = (uint32_t)f2bf(v.x) | ((uint32_t)f2bf(v.y) << 16);
    o.y = (uint32_t)f2bf(v.z) | ((uint32_t)f2bf(v.w) << 16);
    *reinterpret_cast<uint2*>(Xbf + idx) = o;
  } else if (bx < 8192) {
    int b2 = bx - 4096;
    int z = b2 >> 10;
    b2 &= 1023;
    const float* src = z == 0 ? W_Q : (z == 1 ? W_K : (z == 2 ? W_V : W_O));
    u16* dst = z < 3 ? dqkv + (size_t)z * 1024 * 1024 : dwo;
    int c0 = (b2 & 31) * 32, r0 = (b2 >> 5) * 32;
    int tx = t & 31, ty = t >> 5;
#pragma unroll
    for (int i = 0; i < 4; ++i)
      tile[ty + i * 8][tx] = src[(size_t)(r0 + ty + i * 8) * 1024 + c0 + tx];
    __syncthreads();
#pragma unroll
    for (int i = 0; i < 4; ++i)
      dst[(size_t)(c0 + ty + i * 8) * 1024 + r0 + tx] = f2bf(tile[tx][ty + i * 8]);
  } else {
    int idx = (bx - 8192) * 4 + (t >> 6);
    int ln = t & 63;
    int b = idx >> 5, j = idx & 31;
    unsigned long long m = __ballot(ids[b * 2048 + j * 64 + ln] == 0);
    if (ln == 0) pb[idx] = m;
  }
}

// ---------------- GEMM core (m97 structure) ----------------

__device__ __forceinline__ void gemm_tile_acc(
    const u16* __restrict__ A, const u16* __restrict__ Bt, int K,
    int tm, int tn, u16* As, u16* Bs, f32x4 acc[4][4]) {
  const int t = threadIdx.x, wv = t >> 6, ln = t & 63;
  const int wr = (wv & 1) * 64, wc = (wv >> 1) * 64;
  const int lr = ln & 15, q8 = (ln >> 4) * 8;
  const int srow = ln >> 2, scol = (ln & 3) * 8;

  for (int k0 = 0; k0 < K; k0 += 32) {
#pragma unroll
    for (int i = 0; i < 2; ++i) {
      int c = wv + i * 4;
      gl_lds16(A + (size_t)(tm + c * 16 + srow) * K + k0 + scol, As + c * 512 + ln * 8);
      gl_lds16(Bt + (size_t)(tn + c * 16 + srow) * K + k0 + scol, Bs + c * 512 + ln * 8);
    }
    __syncthreads();
    bf16x8 av[4], bv[4];
#pragma unroll
    for (int m = 0; m < 4; ++m)
      av[m] = *reinterpret_cast<const bf16x8*>(As + (wr + m * 16 + lr) * 32 + q8);
#pragma unroll
    for (int n = 0; n < 4; ++n)
      bv[n] = *reinterpret_cast<const bf16x8*>(Bs + (wc + n * 16 + lr) * 32 + q8);
#pragma unroll
    for (int m = 0; m < 4; ++m)
#pragma unroll
      for (int n = 0; n < 4; ++n)
        acc[m][n] = __builtin_amdgcn_mfma_f32_16x16x32_bf16(av[m], bv[n], acc[m][n], 0, 0, 0);
    __syncthreads();
  }
}

// QKV projection into fragment-ready tiled layouts (see header comment).
__global__ __launch_bounds__(256) void k_qkv(
    const u16* __restrict__ X, const u16* __restrict__ Wt,
    const float* __restrict__ bQ, const float* __restrict__ bK, const float* __restrict__ bV,
    u16* __restrict__ Qt, u16* __restrict__ Kt, u16* __restrict__ Vt) {
  __shared__ __align__(16) u16 As[128 * 32];
  __shared__ __align__(16) u16 Bs[128 * 32];
  f32x4 acc[4][4] = {};
  const int tm = blockIdx.x * 128, tn = blockIdx.y * 128;
  gemm_tile_acc(X, Wt, 1024, tm, tn, As, Bs, acc);

  const int t = threadIdx.x, wv = t >> 6, ln = t & 63;
  const int wr = (wv & 1) * 64, wc = (wv >> 1) * 64;
  const int lr = ln & 15, q4 = (ln >> 4) * 4;
  const int which = tn >> 10;

  if (which == 0) {  // Q, pre-scaled by SCL
#pragma unroll
    for (int n = 0; n < 4; ++n) {
      int f = (tn + wc + n * 16 + lr) & 1023;
      float bb = bQ[f];
      int h = f >> 6, dd = f & 63;
      int kh = dd >> 5, qq = (dd & 31) >> 3, e = dd & 7;
#pragma unroll
      for (int m = 0; m < 4; ++m)
#pragma unroll
        for (int r = 0; r < 4; ++r) {
          int gr = tm + wr + m * 16 + q4 + r;
          int b = gr >> 11, s = gr & 2047;
          int bh = b * 16 + h;
          size_t addr = (((size_t)(bh * 64 + (s >> 5)) * 4 + ((s & 31) >> 4) * 2 + kh) << 9) +
                        ((s & 15) + 16 * qq) * 8 + e;
          Qt[addr] = f2bf((acc[m][n][r] + bb) * SCL);
        }
    }
  } else if (which == 1) {  // K
#pragma unroll
    for (int n = 0; n < 4; ++n) {
      int f = (tn + wc + n * 16 + lr) & 1023;
      float bb = bK[f];
      int h = f >> 6, dd = f & 63;
      int kh = dd >> 5, qq = (dd & 31) >> 3, e = dd & 7;
#pragma unroll
      for (int m = 0; m < 4; ++m)
#pragma unroll
        for (int r = 0; r < 4; ++r) {
          int gr = tm + wr + m * 16 + q4 + r;
          int b = gr >> 11, s = gr & 2047;
          int bh = b * 16 + h;
          size_t addr = (((size_t)(bh * 32 + (s >> 6)) * 8 + kh * 4 + ((s & 63) >> 4)) << 9) +
                        ((s & 15) + 16 * qq) * 8 + e;
          Kt[addr] = f2bf(acc[m][n][r] + bb);
        }
    }
  } else {  // V -> V^T fragment tiles, 4 contiguous k-elems per packed store
#pragma unroll
    for (int n = 0; n < 4; ++n) {
      int f = (tn + wc + n * 16 + lr) & 1023;
      float bb = bV[f];
      int h = f >> 6, dd = f & 63;
      int md = dd >> 4, lrv = dd & 15;
#pragma unroll
      for (int m = 0; m < 4; ++m) {
        int gr0 = tm + wr + m * 16 + q4;
        int b = gr0 >> 11, s0 = gr0 & 2047;
        int bh = b * 16 + h;
        int j = s0 >> 6, kh = (s0 & 63) >> 5, qv = (s0 & 31) >> 3, e0 = s0 & 7;
        size_t addr = (((size_t)(bh * 32 + j) * 8 + kh * 4 + md) << 9) +
                      (lrv + 16 * qv) * 8 + e0;
        uint2 pk;
        pk.x = (uint32_t)f2bf(acc[m][n][0] + bb) | ((uint32_t)f2bf(acc[m][n][1] + bb) << 16);
        pk.y = (uint32_t)f2bf(acc[m][n][2] + bb) | ((uint32_t)f2bf(acc[m][n][3] + bb) << 16);
        *reinterpret_cast<uint2*>(Vt + addr) = pk;
      }
    }
  }
}

// Output projection -> fp32 out
__global__ __launch_bounds__(256) void k_out(
    const u16* __restrict__ O, const u16* __restrict__ WoT,
    const float* __restrict__ bO, float* __restrict__ out) {
  __shared__ __align__(16) u16 As[128 * 32];
  __shared__ __align__(16) u16 Bs[128 * 32];
  f32x4 acc[4][4] = {};
  const int tm = blockIdx.x * 128, tn = blockIdx.y * 128;
  gemm_tile_acc(O, WoT, 1024, tm, tn, As, Bs, acc);

  const int t = threadIdx.x, wv = t >> 6, ln = t & 63;
  const int wr = (wv & 1) * 64, wc = (wv >> 1) * 64;
  const int lr = ln & 15, q4 = (ln >> 4) * 4;
#pragma unroll
  for (int n = 0; n < 4; ++n) {
    int gc = tn + wc + n * 16 + lr;
    float bb = bO[gc];
#pragma unroll
    for (int m = 0; m < 4; ++m)
#pragma unroll
      for (int r = 0; r < 4; ++r) {
        int gr = tm + wr + m * 16 + q4 + r;
        out[(size_t)gr * 1024 + gc] = acc[m][n][r] + bb;
      }
  }
}

// ---------------- barrier-free, software-pipelined split-K flash attention ----------------
// Same 2560-item band decode. Per iteration j: prefetch K_{j+1} frags; S_j MFMAs;
// softmax_j; ds_write P_j; PV_{j-1} MFMAs (covering the lgkm wait); load V_j frags;
// ds_read P_j frags (consumed next iter). Tail flush does PV_{jte-1}. No __syncthreads.
__global__ __launch_bounds__(128) void k_attn(
    const u16* __restrict__ Qt, const u16* __restrict__ Kt, const u16* __restrict__ Vt,
    const unsigned long long* __restrict__ padbits,
    u16* __restrict__ Opart, float* __restrict__ Lpart) {
  __shared__ __align__(16) u16 Ps[64 * 72];

  const int id = blockIdx.x;
  const int bh = id & 31;
  const int w = 79 - (id >> 5);
  int qi, c;
  if (w < 8)       { qi = w;                   c = 0; }
  else if (w < 24) { qi = 8 + ((w - 8) >> 1);  c = (w - 8) & 1; }
  else if (w < 48) { qi = 16 + (w - 24) / 3;   c = (w - 24) % 3; }
  else             { qi = 24 + ((w - 48) >> 2); c = (w - 48) & 3; }
  const int jts = c * 8;
  const int jte = min(qi + 1, jts + 8);
  const int slot = bh * 80 + w;

  const int bI = bh >> 4;
  const int t = threadIdx.x, wv = t >> 6, ln = t & 63;
  const int lr = ln & 15, q4 = (ln >> 4) * 4, q8 = (ln >> 4) * 8;
  const int qbase = qi * 64 + wv * 32;
  const int qrow = wv * 32;

  // Q B-frags: coalesced from Qt
  bf16x8 bq[2][2];
  {
    const u16* qb = Qt + (((size_t)(bh * 64 + (qbase >> 5)) * 4) << 9) + ln * 8;
#pragma unroll
    for (int n = 0; n < 2; ++n)
#pragma unroll
      for (int kh = 0; kh < 2; ++kh)
        bq[n][kh] = *reinterpret_cast<const bf16x8*>(qb + ((n * 2 + kh) << 9));
  }

  float lo[2] = {0.f, 0.f};
  f32x4 Oc[4][2] = {};

  const u16* Kb = Kt + (((size_t)bh * 32) << 12) + ln * 8;
  const u16* Vb = Vt + (((size_t)bh * 32) << 12) + ln * 8;

  bf16x8 ak0[4], ak1[4];     // K frags, tile j (rotated)
  bf16x8 av0[4], av1[4];     // V frags, tile j (consumed next iter)
  bf16x8 bp0[2], bp1[2];     // P frags, tile j (consumed next iter)
#pragma unroll
  for (int m = 0; m < 4; ++m) {
    ak0[m] = *reinterpret_cast<const bf16x8*>(Kb + ((size_t)jts << 12) + (m << 9));
    ak1[m] = *reinterpret_cast<const bf16x8*>(Kb + ((size_t)jts << 12) + ((4 + m) << 9));
  }

  for (int j = jts; j < jte; ++j) {
    const int kb = j * 64;
    const unsigned long long pb = padbits[bI * 32 + j];
    const bool masked = (kb + 63 > qbase) || (pb != 0);

    // next tile's K frags (register rotation)
    bf16x8 nk0[4], nk1[4];
    if (j + 1 < jte) {
#pragma unroll
      for (int m = 0; m < 4; ++m) {
        nk0[m] = *reinterpret_cast<const bf16x8*>(Kb + ((size_t)(j + 1) << 12) + (m << 9));
        nk1[m] = *reinterpret_cast<const bf16x8*>(Kb + ((size_t)(j + 1) << 12) + ((4 + m) << 9));
      }
    }

    // S'^T = K (Q*SCL)^T
    f32x4 sc[4][2] = {};
#pragma unroll
    for (int m = 0; m < 4; ++m)
#pragma unroll
      for (int n = 0; n < 2; ++n) {
        sc[m][n] = __builtin_amdgcn_mfma_f32_16x16x32_bf16(ak0[m], bq[n][0], sc[m][n], 0, 0, 0);
        sc[m][n] = __builtin_amdgcn_mfma_f32_16x16x32_bf16(ak1[m], bq[n][1], sc[m][n], 0, 0, 0);
      }

    // fixed-max softmax: p = exp2(s'), lane-local l; pack + write P_j to LDS
#pragma unroll
    for (int n = 0; n < 2; ++n) {
      if (masked) {
        const int qabs = qbase + n * 16 + lr;
#pragma unroll
        for (int m = 0; m < 4; ++m)
#pragma unroll
          for (int r = 0; r < 4; ++r) {
            const int sl = m * 16 + q4 + r;
            const bool dead = (kb + sl > qabs) || ((pb >> sl) & 1ull);
            sc[m][n][r] = dead ? -1e30f : sc[m][n][r];
          }
      }
      float ps = 0.f;
#pragma unroll
      for (int m = 0; m < 4; ++m) {
        float p0 = exp2f(sc[m][n][0]);
        float p1 = exp2f(sc[m][n][1]);
        float p2 = exp2f(sc[m][n][2]);
        float p3 = exp2f(sc[m][n][3]);
        ps += (p0 + p1) + (p2 + p3);
        uint2 pk;  // truncation pack via v_perm
        pk.x = __builtin_amdgcn_perm(__float_as_uint(p1), __float_as_uint(p0), 0x07060302);
        pk.y = __builtin_amdgcn_perm(__float_as_uint(p3), __float_as_uint(p2), 0x07060302);
        *reinterpret_cast<uint2*>(Ps + (qrow + n * 16 + lr) * 72 + m * 16 + q4) = pk;
      }
      lo[n] += ps;
    }

    // PV for PREVIOUS tile — covers the ds_write->ds_read lgkm wait of P_j
    if (j > jts) {
#pragma unroll
      for (int n = 0; n < 2; ++n)
#pragma unroll
        for (int md = 0; md < 4; ++md) {
          Oc[md][n] = __builtin_amdgcn_mfma_f32_16x16x32_bf16(av0[md], bp0[n], Oc[md][n], 0, 0, 0);
          Oc[md][n] = __builtin_amdgcn_mfma_f32_16x16x32_bf16(av1[md], bp1[n], Oc[md][n], 0, 0, 0);
        }
    }

    // V frags for tile j (consumed next iteration / tail)
#pragma unroll
    for (int md = 0; md < 4; ++md) {
      av0[md] = *reinterpret_cast<const bf16x8*>(Vb + ((size_t)j << 12) + (md << 9));
      av1[md] = *reinterpret_cast<const bf16x8*>(Vb + ((size_t)j << 12) + ((4 + md) << 9));
    }
    // read back P_j frags (consumed next iteration / tail)
#pragma unroll
    for (int n = 0; n < 2; ++n) {
      bp0[n] = *reinterpret_cast<const bf16x8*>(Ps + (qrow + n * 16 + lr) * 72 + q8);
      bp1[n] = *reinterpret_cast<const bf16x8*>(Ps + (qrow + n * 16 + lr) * 72 + 32 + q8);
    }

#pragma unroll
    for (int m = 0; m < 4; ++m) { ak0[m] = nk0[m]; ak1[m] = nk1[m]; }
  }

  // pipeline tail: PV for the last tile
#pragma unroll
  for (int n = 0; n < 2; ++n)
#pragma unroll
    for (int md = 0; md < 4; ++md) {
      Oc[md][n] = __builtin_amdgcn_mfma_f32_16x16x32_bf16(av0[md], bp0[n], Oc[md][n], 0, 0, 0);
      Oc[md][n] = __builtin_amdgcn_mfma_f32_16x16x32_bf16(av1[md], bp1[n], Oc[md][n], 0, 0, 0);
    }

  // epilogue: single cross-lane l reduction; O'[q][d] = O^T/l (bf16), l raw fp32
  const size_t obase = (size_t)slot * 4096;
#pragma unroll
  for (int n = 0; n < 2; ++n) {
    lo[n] += __shfl_xor(lo[n], 16, 64);
    lo[n] += __shfl_xor(lo[n], 32, 64);
    const float inv = 1.f / lo[n];
    const int qlocal = qrow + n * 16 + lr;
#pragma unroll
    for (int md = 0; md < 4; ++md) {
      uint2 pk;
      pk.x = (uint32_t)f2bf(Oc[md][n][0] * inv) | ((uint32_t)f2bf(Oc[md][n][1] * inv) << 16);
      pk.y = (uint32_t)f2bf(Oc[md][n][2] * inv) | ((uint32_t)f2bf(Oc[md][n][3] * inv) << 16);
      *reinterpret_cast<uint2*>(Opart + obase + (size_t)qlocal * 64 + md * 16 + q4) = pk;
    }
    if (ln < 16) Lpart[slot * 64 + qlocal] = lo[n];
  }
}

// merge partials: l-weighted average. block per (bh, qi); thread t: q=t>>2, 16 d at (t&3)*16
__global__ __launch_bounds__(256) void k_merge(
    const u16* __restrict__ Opart, const float* __restrict__ Lpart, u16* __restrict__ O) {
  const int bh = blockIdx.x >> 5, qi = blockIdx.x & 31;
  const int nc = (qi >> 3) + 1;
  const int band = qi >> 3;
  const int pre = (band == 0 ? 0 : band == 1 ? 8 : band == 2 ? 24 : 48) + (qi & 7) * (band + 1);
  const int slot0 = bh * 80 + pre;

  const int t = threadIdx.x;
  const int q = t >> 2, ds = (t & 3) * 16;

  float wc[4], wsum = 0.f;
  for (int cI = 0; cI < nc; ++cI) {
    wc[cI] = Lpart[(slot0 + cI) * 64 + q];
    wsum += wc[cI];
  }
  const float inv = 1.f / wsum;

  float acc[16];
#pragma unroll
  for (int e = 0; e < 16; ++e) acc[e] = 0.f;
  for (int cI = 0; cI < nc; ++cI) {
    const u16* src = Opart + (size_t)(slot0 + cI) * 4096 + q * 64 + ds;
    uint4 a = *reinterpret_cast<const uint4*>(src);
    uint4 b = *reinterpret_cast<const uint4*>(src + 8);
    uint32_t uu[8] = {a.x, a.y, a.z, a.w, b.x, b.y, b.z, b.w};
    const float wci = wc[cI];
#pragma unroll
    for (int p = 0; p < 8; ++p) {
      acc[2 * p]     += wci * __uint_as_float(uu[p] << 16);
      acc[2 * p + 1] += wci * __uint_as_float(uu[p] & 0xFFFF0000u);
    }
  }

  const int bI = bh >> 4, hI = bh & 15;
  const size_t row = (size_t)(bI * 2048 + qi * 64 + q);
  u16* dst = O + row * 1024 + hI * 64 + ds;
  uint32_t op[8];
#pragma unroll
  for (int p = 0; p < 8; ++p)
    op[p] = (uint32_t)f2bf(acc[2 * p] * inv) | ((uint32_t)f2bf(acc[2 * p + 1] * inv) << 16);
  *reinterpret_cast<uint4*>(dst) = *reinterpret_cast<const uint4*>(&op[0]);
  *reinterpret_cast<uint4*>(dst + 8) = *reinterpret_cast<const uint4*>(&op[4]);
}

// ---------------- launch ----------------

extern "C" void kernel_launch(void* const* d_in, const int* in_sizes, int n_in,
                              void* d_out, int out_size, void* d_ws, size_t ws_size,
                              hipStream_t stream) {
  (void)in_sizes; (void)n_in; (void)out_size; (void)ws_size;
  const float* batch = (const float*)d_in[0];
  const int* ids     = (const int*)d_in[1];
  const float* W_Q   = (const float*)d_in[2];
  const float* W_K   = (const float*)d_in[3];
  const float* W_V   = (const float*)d_in[4];
  const float* b_Q   = (const float*)d_in[5];
  const float* b_K   = (const float*)d_in[6];
  const float* b_V   = (const float*)d_in[7];
  const float* W_O   = (const float*)d_in[8];
  const float* b_O   = (const float*)d_in[9];
  float* out = (float*)d_out;

  u16* ws = (u16*)d_ws;
  u16* Xbf   = ws;                        // 4,194,304
  u16* WqkvT = Xbf + 4194304;             // 3,145,728 (dead after k_qkv)
  u16* WoT   = WqkvT + 3145728;           // 1,048,576
  u16* Qtb   = WoT + 1048576;             // 4,194,304 (tiled)
  u16* Ktb   = Qtb + 4194304;             // 4,194,304 (tiled)
  u16* Vtb   = Ktb + 4194304;             // 4,194,304 (tiled V^T)
  u16* Opart = Vtb + 4194304;             // 2560*4096 = 10,485,760
  float* Lpart = (float*)WqkvT;           // overlay dead WqkvT (163,840 f32)
  u16* Ob    = Xbf;                       // reuse X after k_qkv

  unsigned long long* padbits =
      (unsigned long long*)((char*)d_out + (size_t)out_size * 4 - 512);

  k_prologue<<<8208, 256, 0, stream>>>(batch, ids, W_Q, W_K, W_V, W_O, Xbf, WqkvT, WoT, padbits);
  k_qkv<<<dim3(32, 24), 256, 0, stream>>>(Xbf, WqkvT, b_Q, b_K, b_V, Qtb, Ktb, Vtb);
  k_attn<<<2560, 128, 0, stream>>>(Qtb, Ktb, Vtb, padbits, Opart, Lpart);
  k_merge<<<1024, 256, 0, stream>>>(Opart, Lpart, Ob);
  k_out<<<dim3(32, 8), 256, 0, stream>>>(Ob, WoT, b_O, out);
}